// Round 7
// baseline (731.061 us; speedup 1.0000x reference)
//
#include <hip/hip_runtime.h>
#include <hip/hip_bf16.h>

#define D_OUT 64
#define K_DIM 512
#define RPB 128            // rows per bucket (pow2)
#define RPB_SHIFT 7
#define GCAP 3072          // global keys capacity per bucket (mean 2046, +22 sigma)
#define RCAP 3072          // LDS record capacity per bucket

using short8  = __attribute__((ext_vector_type(8))) short;
using floatx4 = __attribute__((ext_vector_type(4))) float;

__device__ inline unsigned short f32_to_bf16(float f) {
    __hip_bfloat16 b = __float2bfloat16(f);          // HW RNE cvt
    return *reinterpret_cast<unsigned short*>(&b);
}

__device__ inline unsigned int pk_bf16(float lo, float hi) {
    __hip_bfloat162 p = __float22bfloat162_rn(make_float2(lo, hi));
    return *reinterpret_cast<unsigned int*>(&p);     // low16 = lo, high16 = hi
}

__device__ inline float bf16lo_f32(unsigned int g) {   // low ushort -> f32
    return __uint_as_float(g << 16);
}
__device__ inline float bf16hi_f32(unsigned int g) {   // high ushort -> f32
    return __uint_as_float(g & 0xFFFF0000u);
}

// ---------------------------------------------------------------------------
// Wt[n][k] = bf16(W[k][n]) : 64 x 512 bf16 (64 KB, L2-resident)
__global__ void wt_kernel(const float* __restrict__ W, unsigned short* __restrict__ wt) {
    int i = blockIdx.x * blockDim.x + threadIdx.x;
    if (i < D_OUT * K_DIM) {
        int n = i >> 9;
        int k = i & 511;
        wt[i] = f32_to_bf16(W[k * D_OUT + n]);
    }
}

// ---------------------------------------------------------------------------
// gemm v6: register ping-pong software pipeline. Wave = 16 rows x 64 cols.
// While MFMA consumes chunk c (8 float4/lane), chunk c+1's 8 loads are in
// flight. Fully unrolled; all array indices static (rule #20).
#define ISSUE(T, H0)                                                          \
    _Pragma("unroll")                                                         \
    for (int s = 0; s < 4; s++) {                                             \
        T[2*s]   = *reinterpret_cast<const float4*>(Arow + (H0) + s*32 + quad*8);     \
        T[2*s+1] = *reinterpret_cast<const float4*>(Arow + (H0) + s*32 + quad*8 + 4); \
    }

#define COMPUTE(T, H0)                                                        \
    _Pragma("unroll")                                                         \
    for (int s = 0; s < 4; s++) {                                             \
        float4 a0 = T[2*s], a1 = T[2*s+1];                                    \
        int4 pk;                                                              \
        pk.x = (int)pk_bf16(a0.x, a0.y);                                      \
        pk.y = (int)pk_bf16(a0.z, a0.w);                                      \
        pk.z = (int)pk_bf16(a1.x, a1.y);                                      \
        pk.w = (int)pk_bf16(a1.z, a1.w);                                      \
        short8 af = *reinterpret_cast<short8*>(&pk);                          \
        const int ko = (H0) + s*32 + quad*8;                                  \
        short8 b0 = *reinterpret_cast<const short8*>(wb + ko);                \
        short8 b1 = *reinterpret_cast<const short8*>(wb + 16 * K_DIM + ko);   \
        short8 b2 = *reinterpret_cast<const short8*>(wb + 32 * K_DIM + ko);   \
        short8 b3 = *reinterpret_cast<const short8*>(wb + 48 * K_DIM + ko);   \
        acc0 = __builtin_amdgcn_mfma_f32_16x16x32_bf16(af, b0, acc0, 0, 0, 0);\
        acc1 = __builtin_amdgcn_mfma_f32_16x16x32_bf16(af, b1, acc1, 0, 0, 0);\
        acc2 = __builtin_amdgcn_mfma_f32_16x16x32_bf16(af, b2, acc2, 0, 0, 0);\
        acc3 = __builtin_amdgcn_mfma_f32_16x16x32_bf16(af, b3, acc3, 0, 0, 0);\
    }

__global__ __launch_bounds__(256) void gemm_kernel(
    const float* __restrict__ A, const unsigned short* __restrict__ wt,
    unsigned short* __restrict__ H, int n) {
    const int tid  = threadIdx.x;
    const int wv   = tid >> 6;
    const int lane = tid & 63;
    const int ln   = lane & 15;
    const int quad = lane >> 4;
    const int row0 = blockIdx.x * 64 + wv * 16;

    int arow = row0 + ln;
    if (arow >= n) arow = n - 1;          // clamp (stores guarded)
    const float* Arow = A + (size_t)arow * K_DIM;
    const unsigned short* wb = wt + (size_t)ln * K_DIM;

    floatx4 acc0 = {0.f, 0.f, 0.f, 0.f};
    floatx4 acc1 = {0.f, 0.f, 0.f, 0.f};
    floatx4 acc2 = {0.f, 0.f, 0.f, 0.f};
    floatx4 acc3 = {0.f, 0.f, 0.f, 0.f};

    float4 tA[8], tB[8];
    ISSUE(tA, 0)
    ISSUE(tB, 128)
    COMPUTE(tA, 0)
    ISSUE(tA, 256)
    COMPUTE(tB, 128)
    ISSUE(tB, 384)
    COMPUTE(tA, 256)
    COMPUTE(tB, 384)

    // C/D layout: col = lane&15, row = quad*4 + reg  [m89]
#pragma unroll
    for (int r = 0; r < 4; r++) {
        int gr = row0 + quad * 4 + r;
        if (gr < n) {
            unsigned short* Hr = H + (size_t)gr * D_OUT;
            Hr[ln]      = f32_to_bf16(acc0[r]);
            Hr[16 + ln] = f32_to_bf16(acc1[r]);
            Hr[32 + ln] = f32_to_bf16(acc2[r]);
            Hr[48 + ln] = f32_to_bf16(acc3[r]);
        }
    }
}

// ---------------------------------------------------------------------------
// init: cursor[b] = b * GCAP  (bucket segment bases)
__global__ __launch_bounds__(256) void init_kernel(int* __restrict__ cursor, int nbuck) {
    int b = blockIdx.x * 256 + threadIdx.x;
    if (b < nbuck) cursor[b] = b * GCAP;
}

// ---------------------------------------------------------------------------
// partition: edges -> bucket-grouped packed records (col | rl<<17, val)
// via global per-bucket atomic cursors (782 hot L2 counters). Replaces
// count + 3 scan kernels + the chunked partition.
__global__ __launch_bounds__(256) void partition_kernel(
    const int* __restrict__ rows, const int* __restrict__ cols,
    const float* __restrict__ vals, int* __restrict__ cursor,
    int2* __restrict__ keys, int E) {
    int i = blockIdx.x * 256 + threadIdx.x;
    const int stride = gridDim.x * 256;
    for (; i < E; i += stride) {
        int r = rows[i];
        int c = cols[i];
        float v = vals[i];
        int b = r >> RPB_SHIFT;
        int p = atomicAdd(&cursor[b], 1);
        if (p < (b + 1) * GCAP)          // drop on (practically impossible) overflow
            keys[p] = make_int2(c | ((r & (RPB - 1)) << 17), __float_as_int(v));
    }
}

// ---------------------------------------------------------------------------
// P4: one block per bucket. LDS counting sort by row-local, then wave-per-row
// register accumulation (no atomics in hot loop), fused ReLU store.
// Gather: 16 lanes/edge, uint2 = 4 bf16 cols/lane; 128 B = one line per edge.
__global__ __launch_bounds__(512) void sort_agg_kernel(
    const unsigned short* __restrict__ h, const int2* __restrict__ keys,
    const int* __restrict__ cursor, float* __restrict__ out, int N) {
    __shared__ int2 rec[RCAP];
    __shared__ int cnt[RPB];
    __shared__ int excl[RPB];
    __shared__ int cur[RPB];
    __shared__ int wtot[2];

    const int tid  = threadIdx.x;
    const int lane = tid & 63;
    const int wv   = tid >> 6;           // 0..7
    const int q    = lane >> 4;          // 0..3  : edge slot within wave
    const int li   = lane & 15;          // 0..15 : 4 cols per lane
    const int b    = blockIdx.x;

    const int start = b * GCAP;
    int m = cursor[b] - start;           // final cursor = start + count
    if (m > GCAP) m = GCAP;

    if (tid < RPB) cnt[tid] = 0;
    __syncthreads();

    // count rows
    for (int i = tid; i < m; i += 512) {
        int rl = keys[start + i].x >> 17;
        atomicAdd(&cnt[rl], 1);
    }
    __syncthreads();

    // exclusive scan of 128 counters (2 waves)
    int v = 0, x = 0;
    if (tid < RPB) {
        v = cnt[tid];
        x = v;
#pragma unroll
        for (int d = 1; d < 64; d <<= 1) {
            int y = __shfl_up(x, d, 64);
            if (lane >= d) x += y;
        }
        if (lane == 63) wtot[tid >> 6] = x;
    }
    __syncthreads();
    if (tid < RPB) {
        int base = (tid >= 64) ? wtot[0] : 0;
        int ex = base + x - v;
        excl[tid] = ex;
        cur[tid]  = ex;
    }
    __syncthreads();

    // scatter into row-sorted LDS positions
    for (int i = tid; i < m; i += 512) {
        int2 kv = keys[start + i];
        int rl = kv.x >> 17;
        int p = atomicAdd(&cur[rl], 1);
        if (p < RCAP) rec[p] = kv;
    }
    __syncthreads();

    // aggregate: wave per row; 4 edges per load instruction, 8 in flight.
    const int row0 = b * RPB;
    for (int rl = wv; rl < RPB; rl += 8) {
        int s = excl[rl];
        int e = cur[rl];                 // = excl + count
        float4 acc = {0.f, 0.f, 0.f, 0.f};
        int j = s;
        for (; j + 8 <= e; j += 8) {
            int2 kA = rec[j + q];
            int2 kB = rec[j + 4 + q];
            const uint2 gA = *reinterpret_cast<const uint2*>(
                h + (size_t)(kA.x & 0x1FFFF) * D_OUT + li * 4);
            const uint2 gB = *reinterpret_cast<const uint2*>(
                h + (size_t)(kB.x & 0x1FFFF) * D_OUT + li * 4);
            float vA = __int_as_float(kA.y);
            float vB = __int_as_float(kB.y);
            acc.x += vA * bf16lo_f32(gA.x);
            acc.y += vA * bf16hi_f32(gA.x);
            acc.z += vA * bf16lo_f32(gA.y);
            acc.w += vA * bf16hi_f32(gA.y);
            acc.x += vB * bf16lo_f32(gB.x);
            acc.y += vB * bf16hi_f32(gB.x);
            acc.z += vB * bf16lo_f32(gB.y);
            acc.w += vB * bf16hi_f32(gB.y);
        }
        for (; j < e; j += 4) {
            bool on = (j + q) < e;
            int2 kv = rec[on ? j + q : j];     // j < e, so rec[j] is safe
            const uint2 g = *reinterpret_cast<const uint2*>(
                h + (size_t)(kv.x & 0x1FFFF) * D_OUT + li * 4);
            float vv = on ? __int_as_float(kv.y) : 0.f;
            acc.x += vv * bf16lo_f32(g.x);
            acc.y += vv * bf16hi_f32(g.x);
            acc.z += vv * bf16lo_f32(g.y);
            acc.w += vv * bf16hi_f32(g.y);
        }
        // combine the 4 edge slots (xor 16, then 32)
        acc.x += __shfl_xor(acc.x, 16, 64);
        acc.y += __shfl_xor(acc.y, 16, 64);
        acc.z += __shfl_xor(acc.z, 16, 64);
        acc.w += __shfl_xor(acc.w, 16, 64);
        acc.x += __shfl_xor(acc.x, 32, 64);
        acc.y += __shfl_xor(acc.y, 32, 64);
        acc.z += __shfl_xor(acc.z, 32, 64);
        acc.w += __shfl_xor(acc.w, 32, 64);

        if (q == 0) {
            int gr = row0 + rl;
            if (gr < N) {
                float4 o;
                o.x = fmaxf(acc.x, 0.f);
                o.y = fmaxf(acc.y, 0.f);
                o.z = fmaxf(acc.z, 0.f);
                o.w = fmaxf(acc.w, 0.f);
                *reinterpret_cast<float4*>(out + (size_t)gr * D_OUT + li * 4) = o;
            }
        }
    }
}

// ---------------------------------------------------------------------------
extern "C" void kernel_launch(void* const* d_in, const int* in_sizes, int n_in,
                              void* d_out, int out_size, void* d_ws, size_t ws_size,
                              hipStream_t stream) {
    const float* A    = (const float*)d_in[0];
    const float* W    = (const float*)d_in[1];
    const float* vals = (const float*)d_in[2];
    const int*   rows = (const int*)d_in[3];
    const int*   cols = (const int*)d_in[4];
    float* out = (float*)d_out;

    const int N = out_size / D_OUT;                 // 100000
    const int E = in_sizes[2];                      // 1600000
    const int nbuck = (N + RPB - 1) >> RPB_SHIFT;   // 782

    // workspace layout (keys 8-aligned; h is bf16)
    char* ws = (char*)d_ws;
    unsigned short* h      = (unsigned short*)ws;                          // N*64 bf16
    int2*           keys   = (int2*)(ws + (size_t)N * D_OUT * 2);          // nbuck*GCAP int2
    unsigned short* wt     = (unsigned short*)((char*)keys + (size_t)nbuck * GCAP * 8);
    int*            cursor = (int*)((char*)wt + (size_t)D_OUT * K_DIM * 2); // nbuck

    wt_kernel<<<(D_OUT * K_DIM + 255) / 256, 256, 0, stream>>>(W, wt);
    gemm_kernel<<<(N + 63) / 64, 256, 0, stream>>>(A, wt, h, N);
    init_kernel<<<(nbuck + 255) / 256, 256, 0, stream>>>(cursor, nbuck);
    partition_kernel<<<1024, 256, 0, stream>>>(rows, cols, vals, cursor, keys, E);
    sort_agg_kernel<<<nbuck, 512, 0, stream>>>(h, keys, cursor, out, N);
}

// Round 8
// 410.945 us; speedup vs baseline: 1.7790x; 1.7790x over previous
//
#include <hip/hip_runtime.h>
#include <hip/hip_bf16.h>

#define D_OUT 64
#define K_DIM 512
#define RPB 128            // rows per bucket (pow2)
#define RPB_SHIFT 7
#define EPB 8192           // edges per partition chunk
#define GCAP 3072          // keys capacity per bucket (mean 2046, +22 sigma)
#define RCAP 3072          // LDS record capacity per bucket
#define CPAD 16            // cursor padding: 16 ints = 64 B per counter

using short8  = __attribute__((ext_vector_type(8))) short;
using floatx4 = __attribute__((ext_vector_type(4))) float;

__device__ inline unsigned short f32_to_bf16(float f) {
    __hip_bfloat16 b = __float2bfloat16(f);          // HW RNE cvt
    return *reinterpret_cast<unsigned short*>(&b);
}

__device__ inline unsigned int pk_bf16(float lo, float hi) {
    __hip_bfloat162 p = __float22bfloat162_rn(make_float2(lo, hi));
    return *reinterpret_cast<unsigned int*>(&p);     // low16 = lo, high16 = hi
}

__device__ inline float bf16lo_f32(unsigned int g) {   // low ushort -> f32
    return __uint_as_float(g << 16);
}
__device__ inline float bf16hi_f32(unsigned int g) {   // high ushort -> f32
    return __uint_as_float(g & 0xFFFF0000u);
}

// ---------------------------------------------------------------------------
// Wt[n][k] = bf16(W[k][n]) : 64 x 512 bf16 (64 KB, L2-resident)
__global__ void wt_kernel(const float* __restrict__ W, unsigned short* __restrict__ wt) {
    int i = blockIdx.x * blockDim.x + threadIdx.x;
    if (i < D_OUT * K_DIM) {
        int n = i >> 9;
        int k = i & 511;
        wt[i] = f32_to_bf16(W[k * D_OUT + n]);
    }
}

// ---------------------------------------------------------------------------
// gemm (round-4 proven): wave = 16 rows x 64 cols; batch-issued A loads;
// packed HW bf16 cvt; H stored bf16.
__global__ __launch_bounds__(256) void gemm_kernel(
    const float* __restrict__ A, const unsigned short* __restrict__ wt,
    unsigned short* __restrict__ H, int n) {
    const int tid  = threadIdx.x;
    const int wv   = tid >> 6;
    const int lane = tid & 63;
    const int ln   = lane & 15;
    const int quad = lane >> 4;
    const int row0 = blockIdx.x * 64 + wv * 16;

    int arow = row0 + ln;
    if (arow >= n) arow = n - 1;          // clamp (stores guarded)
    const float* Arow = A + (size_t)arow * K_DIM;
    const unsigned short* wb = wt + (size_t)ln * K_DIM;

    floatx4 acc0 = {0.f, 0.f, 0.f, 0.f};
    floatx4 acc1 = {0.f, 0.f, 0.f, 0.f};
    floatx4 acc2 = {0.f, 0.f, 0.f, 0.f};
    floatx4 acc3 = {0.f, 0.f, 0.f, 0.f};

    for (int h0 = 0; h0 < K_DIM; h0 += 128) {
        // issue all 8 A-loads for this 128-k chunk (independent, batched)
        float4 t[8];
#pragma unroll
        for (int s = 0; s < 4; s++) {
            t[2 * s]     = *reinterpret_cast<const float4*>(Arow + h0 + s * 32 + quad * 8);
            t[2 * s + 1] = *reinterpret_cast<const float4*>(Arow + h0 + s * 32 + quad * 8 + 4);
        }
        // convert to bf16 fragments (packed v_cvt_pk_bf16_f32)
        short8 ab[4];
#pragma unroll
        for (int s = 0; s < 4; s++) {
            float4 a0 = t[2 * s], a1 = t[2 * s + 1];
            int4 pk;
            pk.x = (int)pk_bf16(a0.x, a0.y);
            pk.y = (int)pk_bf16(a0.z, a0.w);
            pk.z = (int)pk_bf16(a1.x, a1.y);
            pk.w = (int)pk_bf16(a1.z, a1.w);
            ab[s] = *reinterpret_cast<short8*>(&pk);
        }
        // MFMA over the 4 k-steps (B from L2-hot Wt)
#pragma unroll
        for (int s = 0; s < 4; s++) {
            const int ko = h0 + s * 32 + quad * 8;
            short8 b0 = *reinterpret_cast<const short8*>(wb + ko);
            short8 b1 = *reinterpret_cast<const short8*>(wb + 16 * K_DIM + ko);
            short8 b2 = *reinterpret_cast<const short8*>(wb + 32 * K_DIM + ko);
            short8 b3 = *reinterpret_cast<const short8*>(wb + 48 * K_DIM + ko);
            acc0 = __builtin_amdgcn_mfma_f32_16x16x32_bf16(ab[s], b0, acc0, 0, 0, 0);
            acc1 = __builtin_amdgcn_mfma_f32_16x16x32_bf16(ab[s], b1, acc1, 0, 0, 0);
            acc2 = __builtin_amdgcn_mfma_f32_16x16x32_bf16(ab[s], b2, acc2, 0, 0, 0);
            acc3 = __builtin_amdgcn_mfma_f32_16x16x32_bf16(ab[s], b3, acc3, 0, 0, 0);
        }
    }

    // C/D layout: col = lane&15, row = quad*4 + reg  [m89]
#pragma unroll
    for (int r = 0; r < 4; r++) {
        int gr = row0 + quad * 4 + r;
        if (gr < n) {
            unsigned short* Hr = H + (size_t)gr * D_OUT;
            Hr[ln]      = f32_to_bf16(acc0[r]);
            Hr[16 + ln] = f32_to_bf16(acc1[r]);
            Hr[32 + ln] = f32_to_bf16(acc2[r]);
            Hr[48 + ln] = f32_to_bf16(acc3[r]);
        }
    }
}

// ---------------------------------------------------------------------------
// init: cursor[b*CPAD] = b * GCAP  (64 B-padded bucket segment cursors)
__global__ __launch_bounds__(256) void init_kernel(int* __restrict__ cursor, int nbuck) {
    int b = blockIdx.x * 256 + threadIdx.x;
    if (b < nbuck) cursor[b * CPAD] = b * GCAP;
}

// ---------------------------------------------------------------------------
// Fused count + scan + partition. One block per 8192-edge chunk:
//   phase 1: LDS histogram of the chunk (round-1 count machinery)
//   phase 2: ONE global atomicAdd per non-empty (chunk,bucket) reserves a
//            contiguous run in bucket b's segment (~196 ops/counter, 64 B-
//            padded counters -> no same-address storm, no false sharing)
//   phase 3: scatter via LDS offsets (round-1 partition machinery)
// Replaces count + scan1/2/3 + partition (5 kernels -> 1); rows chunk stays
// L1/L2-hot across the two passes.
__global__ __launch_bounds__(256) void part_kernel(
    const int* __restrict__ rows, const int* __restrict__ cols,
    const float* __restrict__ vals, int* __restrict__ cursor,
    int2* __restrict__ keys, int E, int nbuck) {
    extern __shared__ int sm[];
    int* cnt  = sm;            // [nbuck]
    int* offs = sm + nbuck;    // [nbuck]
    const int tid = threadIdx.x, blk = blockIdx.x;

    for (int b = tid; b < nbuck; b += 256) cnt[b] = 0;
    __syncthreads();

    const int base = blk * EPB;
#pragma unroll
    for (int i = 0; i < EPB / 256; i++) {
        int e = base + tid + i * 256;
        if (e < E) atomicAdd(&cnt[rows[e] >> RPB_SHIFT], 1);
    }
    __syncthreads();

    // reserve a run per non-empty bucket
    for (int b = tid; b < nbuck; b += 256) {
        int c = cnt[b];
        offs[b] = c ? atomicAdd(&cursor[b * CPAD], c) : 0;
    }
    __syncthreads();

    // scatter (bucket-grouped, ~84 B contiguous runs)
#pragma unroll
    for (int i = 0; i < EPB / 256; i++) {
        int e = base + tid + i * 256;
        if (e < E) {
            int r = rows[e];
            int c = cols[e];
            float v = vals[e];
            int b = r >> RPB_SHIFT;
            int p = atomicAdd(&offs[b], 1);
            if (p < (b + 1) * GCAP)          // (practically impossible) overflow guard
                keys[p] = make_int2(c | ((r & (RPB - 1)) << 17), __float_as_int(v));
        }
    }
}

// ---------------------------------------------------------------------------
// P4 (round-1 proven): one block per bucket. LDS counting sort by row-local,
// then wave-per-row register accumulation, fused ReLU store.
// Gather: 16 lanes/edge, uint2 = 4 bf16 cols/lane; 128 B = one line per edge.
__global__ __launch_bounds__(512) void sort_agg_kernel(
    const unsigned short* __restrict__ h, const int2* __restrict__ keys,
    const int* __restrict__ cursor, float* __restrict__ out, int N) {
    __shared__ int2 rec[RCAP];
    __shared__ int cnt[RPB];
    __shared__ int excl[RPB];
    __shared__ int cur[RPB];
    __shared__ int wtot[2];

    const int tid  = threadIdx.x;
    const int lane = tid & 63;
    const int wv   = tid >> 6;           // 0..7
    const int q    = lane >> 4;          // 0..3  : edge slot within wave
    const int li   = lane & 15;          // 0..15 : 4 cols per lane
    const int b    = blockIdx.x;

    const int start = b * GCAP;
    int m = cursor[b * CPAD] - start;    // final cursor = start + count
    if (m > GCAP) m = GCAP;

    if (tid < RPB) cnt[tid] = 0;
    __syncthreads();

    // count rows
    for (int i = tid; i < m; i += 512) {
        int rl = keys[start + i].x >> 17;
        atomicAdd(&cnt[rl], 1);
    }
    __syncthreads();

    // exclusive scan of 128 counters (2 waves)
    int v = 0, x = 0;
    if (tid < RPB) {
        v = cnt[tid];
        x = v;
#pragma unroll
        for (int d = 1; d < 64; d <<= 1) {
            int y = __shfl_up(x, d, 64);
            if (lane >= d) x += y;
        }
        if (lane == 63) wtot[tid >> 6] = x;
    }
    __syncthreads();
    if (tid < RPB) {
        int base = (tid >= 64) ? wtot[0] : 0;
        int ex = base + x - v;
        excl[tid] = ex;
        cur[tid]  = ex;
    }
    __syncthreads();

    // scatter into row-sorted LDS positions
    for (int i = tid; i < m; i += 512) {
        int2 kv = keys[start + i];
        int rl = kv.x >> 17;
        int p = atomicAdd(&cur[rl], 1);
        if (p < RCAP) rec[p] = kv;
    }
    __syncthreads();

    // aggregate: wave per row; 4 edges per load instruction, 8 in flight.
    const int row0 = b * RPB;
    for (int rl = wv; rl < RPB; rl += 8) {
        int s = excl[rl];
        int e = cur[rl];                 // = excl + count
        float4 acc = {0.f, 0.f, 0.f, 0.f};
        int j = s;
        for (; j + 8 <= e; j += 8) {
            int2 kA = rec[j + q];
            int2 kB = rec[j + 4 + q];
            const uint2 gA = *reinterpret_cast<const uint2*>(
                h + (size_t)(kA.x & 0x1FFFF) * D_OUT + li * 4);
            const uint2 gB = *reinterpret_cast<const uint2*>(
                h + (size_t)(kB.x & 0x1FFFF) * D_OUT + li * 4);
            float vA = __int_as_float(kA.y);
            float vB = __int_as_float(kB.y);
            acc.x += vA * bf16lo_f32(gA.x);
            acc.y += vA * bf16hi_f32(gA.x);
            acc.z += vA * bf16lo_f32(gA.y);
            acc.w += vA * bf16hi_f32(gA.y);
            acc.x += vB * bf16lo_f32(gB.x);
            acc.y += vB * bf16hi_f32(gB.x);
            acc.z += vB * bf16lo_f32(gB.y);
            acc.w += vB * bf16hi_f32(gB.y);
        }
        for (; j < e; j += 4) {
            bool on = (j + q) < e;
            int2 kv = rec[on ? j + q : j];     // j < e, so rec[j] is safe
            const uint2 g = *reinterpret_cast<const uint2*>(
                h + (size_t)(kv.x & 0x1FFFF) * D_OUT + li * 4);
            float vv = on ? __int_as_float(kv.y) : 0.f;
            acc.x += vv * bf16lo_f32(g.x);
            acc.y += vv * bf16hi_f32(g.x);
            acc.z += vv * bf16lo_f32(g.y);
            acc.w += vv * bf16hi_f32(g.y);
        }
        // combine the 4 edge slots (xor 16, then 32)
        acc.x += __shfl_xor(acc.x, 16, 64);
        acc.y += __shfl_xor(acc.y, 16, 64);
        acc.z += __shfl_xor(acc.z, 16, 64);
        acc.w += __shfl_xor(acc.w, 16, 64);
        acc.x += __shfl_xor(acc.x, 32, 64);
        acc.y += __shfl_xor(acc.y, 32, 64);
        acc.z += __shfl_xor(acc.z, 32, 64);
        acc.w += __shfl_xor(acc.w, 32, 64);

        if (q == 0) {
            int gr = row0 + rl;
            if (gr < N) {
                float4 o;
                o.x = fmaxf(acc.x, 0.f);
                o.y = fmaxf(acc.y, 0.f);
                o.z = fmaxf(acc.z, 0.f);
                o.w = fmaxf(acc.w, 0.f);
                *reinterpret_cast<float4*>(out + (size_t)gr * D_OUT + li * 4) = o;
            }
        }
    }
}

// ---------------------------------------------------------------------------
extern "C" void kernel_launch(void* const* d_in, const int* in_sizes, int n_in,
                              void* d_out, int out_size, void* d_ws, size_t ws_size,
                              hipStream_t stream) {
    const float* A    = (const float*)d_in[0];
    const float* W    = (const float*)d_in[1];
    const float* vals = (const float*)d_in[2];
    const int*   rows = (const int*)d_in[3];
    const int*   cols = (const int*)d_in[4];
    float* out = (float*)d_out;

    const int N = out_size / D_OUT;                 // 100000
    const int E = in_sizes[2];                      // 1600000
    const int nbuck = (N + RPB - 1) >> RPB_SHIFT;   // 782
    const int nb = (E + EPB - 1) / EPB;             // 196

    // workspace layout (keys 8-aligned; h is bf16)
    char* ws = (char*)d_ws;
    unsigned short* h      = (unsigned short*)ws;                          // N*64 bf16
    int2*           keys   = (int2*)(ws + (size_t)N * D_OUT * 2);          // nbuck*GCAP int2
    unsigned short* wt     = (unsigned short*)((char*)keys + (size_t)nbuck * GCAP * 8);
    int*            cursor = (int*)((char*)wt + (size_t)D_OUT * K_DIM * 2); // nbuck*CPAD

    const size_t part_lds = (size_t)nbuck * 4 * 2;  // cnt + offs

    wt_kernel<<<(D_OUT * K_DIM + 255) / 256, 256, 0, stream>>>(W, wt);
    gemm_kernel<<<(N + 63) / 64, 256, 0, stream>>>(A, wt, h, N);
    init_kernel<<<(nbuck + 255) / 256, 256, 0, stream>>>(cursor, nbuck);
    part_kernel<<<nb, 256, part_lds, stream>>>(rows, cols, vals, cursor, keys, E, nbuck);
    sort_agg_kernel<<<nbuck, 512, 0, stream>>>(h, keys, cursor, out, N);
}

// Round 9
// 405.765 us; speedup vs baseline: 1.8017x; 1.0128x over previous
//
#include <hip/hip_runtime.h>
#include <hip/hip_bf16.h>

#define D_OUT 64
#define K_DIM 512
#define RPB 128            // rows per bucket (pow2)
#define RPB_SHIFT 7
#define EPB 8192           // edges per partition chunk
#define GCAP 3072          // keys capacity per bucket (mean 2046, +22 sigma)
#define RCAP 3072          // LDS record capacity per bucket
#define CPAD 16            // cursor padding: 16 ints = 64 B per counter
#define NBK 1024           // padded bucket-array capacity (782 actual)

using short8  = __attribute__((ext_vector_type(8))) short;
using floatx4 = __attribute__((ext_vector_type(4))) float;

__device__ inline unsigned short f32_to_bf16(float f) {
    __hip_bfloat16 b = __float2bfloat16(f);          // HW RNE cvt
    return *reinterpret_cast<unsigned short*>(&b);
}

__device__ inline unsigned int pk_bf16(float lo, float hi) {
    __hip_bfloat162 p = __float22bfloat162_rn(make_float2(lo, hi));
    return *reinterpret_cast<unsigned int*>(&p);     // low16 = lo, high16 = hi
}

__device__ inline float bf16lo_f32(unsigned int g) {   // low ushort -> f32
    return __uint_as_float(g << 16);
}
__device__ inline float bf16hi_f32(unsigned int g) {   // high ushort -> f32
    return __uint_as_float(g & 0xFFFF0000u);
}

// ---------------------------------------------------------------------------
// Wt[n][k] = bf16(W[k][n]) : 64 x 512 bf16 (64 KB, L2-resident)
// + fused cursor init (bucket segment bases, 64 B-padded)
__global__ void wt_kernel(const float* __restrict__ W, unsigned short* __restrict__ wt,
                          int* __restrict__ cursor, int nbuck) {
    int i = blockIdx.x * blockDim.x + threadIdx.x;
    if (i < D_OUT * K_DIM) {
        int n = i >> 9;
        int k = i & 511;
        wt[i] = f32_to_bf16(W[k * D_OUT + n]);
    }
    if (i < nbuck) cursor[i * CPAD] = i * GCAP;
}

// ---------------------------------------------------------------------------
// gemm (round-4/8 proven, FROZEN): wave = 16 rows x 64 cols; batch-issued A
// loads; packed HW bf16 cvt; H stored bf16.
__global__ __launch_bounds__(256) void gemm_kernel(
    const float* __restrict__ A, const unsigned short* __restrict__ wt,
    unsigned short* __restrict__ H, int n) {
    const int tid  = threadIdx.x;
    const int wv   = tid >> 6;
    const int lane = tid & 63;
    const int ln   = lane & 15;
    const int quad = lane >> 4;
    const int row0 = blockIdx.x * 64 + wv * 16;

    int arow = row0 + ln;
    if (arow >= n) arow = n - 1;          // clamp (stores guarded)
    const float* Arow = A + (size_t)arow * K_DIM;
    const unsigned short* wb = wt + (size_t)ln * K_DIM;

    floatx4 acc0 = {0.f, 0.f, 0.f, 0.f};
    floatx4 acc1 = {0.f, 0.f, 0.f, 0.f};
    floatx4 acc2 = {0.f, 0.f, 0.f, 0.f};
    floatx4 acc3 = {0.f, 0.f, 0.f, 0.f};

    for (int h0 = 0; h0 < K_DIM; h0 += 128) {
        float4 t[8];
#pragma unroll
        for (int s = 0; s < 4; s++) {
            t[2 * s]     = *reinterpret_cast<const float4*>(Arow + h0 + s * 32 + quad * 8);
            t[2 * s + 1] = *reinterpret_cast<const float4*>(Arow + h0 + s * 32 + quad * 8 + 4);
        }
        short8 ab[4];
#pragma unroll
        for (int s = 0; s < 4; s++) {
            float4 a0 = t[2 * s], a1 = t[2 * s + 1];
            int4 pk;
            pk.x = (int)pk_bf16(a0.x, a0.y);
            pk.y = (int)pk_bf16(a0.z, a0.w);
            pk.z = (int)pk_bf16(a1.x, a1.y);
            pk.w = (int)pk_bf16(a1.z, a1.w);
            ab[s] = *reinterpret_cast<short8*>(&pk);
        }
#pragma unroll
        for (int s = 0; s < 4; s++) {
            const int ko = h0 + s * 32 + quad * 8;
            short8 b0 = *reinterpret_cast<const short8*>(wb + ko);
            short8 b1 = *reinterpret_cast<const short8*>(wb + 16 * K_DIM + ko);
            short8 b2 = *reinterpret_cast<const short8*>(wb + 32 * K_DIM + ko);
            short8 b3 = *reinterpret_cast<const short8*>(wb + 48 * K_DIM + ko);
            acc0 = __builtin_amdgcn_mfma_f32_16x16x32_bf16(ab[s], b0, acc0, 0, 0, 0);
            acc1 = __builtin_amdgcn_mfma_f32_16x16x32_bf16(ab[s], b1, acc1, 0, 0, 0);
            acc2 = __builtin_amdgcn_mfma_f32_16x16x32_bf16(ab[s], b2, acc2, 0, 0, 0);
            acc3 = __builtin_amdgcn_mfma_f32_16x16x32_bf16(ab[s], b3, acc3, 0, 0, 0);
        }
    }

    // C/D layout: col = lane&15, row = quad*4 + reg  [m89]
#pragma unroll
    for (int r = 0; r < 4; r++) {
        int gr = row0 + quad * 4 + r;
        if (gr < n) {
            unsigned short* Hr = H + (size_t)gr * D_OUT;
            Hr[ln]      = f32_to_bf16(acc0[r]);
            Hr[16 + ln] = f32_to_bf16(acc1[r]);
            Hr[32 + ln] = f32_to_bf16(acc2[r]);
            Hr[48 + ln] = f32_to_bf16(acc3[r]);
        }
    }
}

// ---------------------------------------------------------------------------
// part v2: fused count + in-block scan + LDS bucket-SORT + run-grouped write.
// Fixes the 6x write amplification measured in r7 (WRITE_SIZE 78 MB for a
// 12.8 MB payload): records are bucket-sorted in LDS first, then emitted with
// a tid-linear copy so consecutive threads write consecutive global bytes
// (full-line coalesced stores). Global reserve = ONE padded atomic per
// non-empty (chunk,bucket) as in r8.
__global__ __launch_bounds__(256) void part_kernel(
    const int* __restrict__ rows, const int* __restrict__ cols,
    const float* __restrict__ vals, int* __restrict__ cursor,
    int2* __restrict__ keys, int E, int nbuck) {
    __shared__ int2 rec[EPB];                 // 64 KB bucket-sorted records
    __shared__ unsigned short bkt[EPB];       // 16 KB bucket id per slot
    __shared__ int cnt[NBK];                  // histogram, then reused as cur
    __shared__ int excl[NBK];                 // in-chunk exclusive offsets
    __shared__ int goff[NBK];                 // reserved global bases
    __shared__ int wsum[4];

    const int tid = threadIdx.x, lane = tid & 63, wid = tid >> 6;
    const int base = blockIdx.x * EPB;
    int m = E - base; if (m > EPB) m = EPB;

    for (int b = tid; b < nbuck; b += 256) cnt[b] = 0;
    __syncthreads();

    // pass 1: histogram (rows only)
    for (int i = tid; i < m; i += 256)
        atomicAdd(&cnt[rows[base + i] >> RPB_SHIFT], 1);
    __syncthreads();

    // exclusive scan of nbuck (<=1024) counters, scan3-style
    int v[4];
#pragma unroll
    for (int j = 0; j < 4; j++) {
        int ix = tid * 4 + j;
        v[j] = (ix < nbuck) ? cnt[ix] : 0;
    }
#pragma unroll
    for (int j = 1; j < 4; j++) v[j] += v[j - 1];
    int t4 = v[3], x = t4;
#pragma unroll
    for (int d = 1; d < 64; d <<= 1) {
        int y = __shfl_up(x, d, 64);
        if (lane >= d) x += y;
    }
    if (lane == 63) wsum[wid] = x;
    __syncthreads();
    if (tid == 0) {
        int a = 0;
#pragma unroll
        for (int w = 0; w < 4; w++) { int tt = wsum[w]; wsum[w] = a; a += tt; }
    }
    __syncthreads();
    int ex0 = wsum[wid] + (x - t4);
#pragma unroll
    for (int j = 0; j < 4; j++) {
        int ix = tid * 4 + j;
        if (ix < nbuck) excl[ix] = ex0 + ((j == 0) ? 0 : v[j - 1]);
    }
    __syncthreads();

    // global reserve per non-empty bucket; reset cnt as scatter cursor
    for (int b = tid; b < nbuck; b += 256) {
        int c = cnt[b];
        goff[b] = c ? atomicAdd(&cursor[b * CPAD], c) : 0;
        cnt[b] = excl[b];
    }
    __syncthreads();

    // pass 2: scatter into bucket-sorted LDS positions
    for (int i = tid; i < m; i += 256) {
        int r = rows[base + i];
        int b = r >> RPB_SHIFT;
        int p = atomicAdd(&cnt[b], 1);
        rec[p] = make_int2(cols[base + i] | ((r & (RPB - 1)) << 17),
                           __float_as_int(vals[base + i]));
        bkt[p] = (unsigned short)b;
    }
    __syncthreads();

    // emit: tid-linear copy -> consecutive threads hit consecutive global
    // addresses within each bucket run (coalesced full-line stores)
    for (int i = tid; i < m; i += 256) {
        int b = bkt[i];
        int p = goff[b] + (i - excl[b]);
        if (p < (b + 1) * GCAP)              // (practically impossible) overflow guard
            keys[p] = rec[i];
    }
}

// ---------------------------------------------------------------------------
// P4 (r8 proven, FROZEN): one block per bucket. LDS counting sort by
// row-local, then wave-per-row register accumulation, fused ReLU store.
__global__ __launch_bounds__(512) void sort_agg_kernel(
    const unsigned short* __restrict__ h, const int2* __restrict__ keys,
    const int* __restrict__ cursor, float* __restrict__ out, int N) {
    __shared__ int2 rec[RCAP];
    __shared__ int cnt[RPB];
    __shared__ int excl[RPB];
    __shared__ int cur[RPB];
    __shared__ int wtot[2];

    const int tid  = threadIdx.x;
    const int lane = tid & 63;
    const int wv   = tid >> 6;           // 0..7
    const int q    = lane >> 4;          // 0..3  : edge slot within wave
    const int li   = lane & 15;          // 0..15 : 4 cols per lane
    const int b    = blockIdx.x;

    const int start = b * GCAP;
    int m = cursor[b * CPAD] - start;    // final cursor = start + count
    if (m > GCAP) m = GCAP;

    if (tid < RPB) cnt[tid] = 0;
    __syncthreads();

    // count rows
    for (int i = tid; i < m; i += 512) {
        int rl = keys[start + i].x >> 17;
        atomicAdd(&cnt[rl], 1);
    }
    __syncthreads();

    // exclusive scan of 128 counters (2 waves)
    int v = 0, x = 0;
    if (tid < RPB) {
        v = cnt[tid];
        x = v;
#pragma unroll
        for (int d = 1; d < 64; d <<= 1) {
            int y = __shfl_up(x, d, 64);
            if (lane >= d) x += y;
        }
        if (lane == 63) wtot[tid >> 6] = x;
    }
    __syncthreads();
    if (tid < RPB) {
        int base = (tid >= 64) ? wtot[0] : 0;
        int ex = base + x - v;
        excl[tid] = ex;
        cur[tid]  = ex;
    }
    __syncthreads();

    // scatter into row-sorted LDS positions
    for (int i = tid; i < m; i += 512) {
        int2 kv = keys[start + i];
        int rl = kv.x >> 17;
        int p = atomicAdd(&cur[rl], 1);
        if (p < RCAP) rec[p] = kv;
    }
    __syncthreads();

    // aggregate: wave per row; 4 edges per load instruction, 8 in flight.
    const int row0 = b * RPB;
    for (int rl = wv; rl < RPB; rl += 8) {
        int s = excl[rl];
        int e = cur[rl];                 // = excl + count
        float4 acc = {0.f, 0.f, 0.f, 0.f};
        int j = s;
        for (; j + 8 <= e; j += 8) {
            int2 kA = rec[j + q];
            int2 kB = rec[j + 4 + q];
            const uint2 gA = *reinterpret_cast<const uint2*>(
                h + (size_t)(kA.x & 0x1FFFF) * D_OUT + li * 4);
            const uint2 gB = *reinterpret_cast<const uint2*>(
                h + (size_t)(kB.x & 0x1FFFF) * D_OUT + li * 4);
            float vA = __int_as_float(kA.y);
            float vB = __int_as_float(kB.y);
            acc.x += vA * bf16lo_f32(gA.x);
            acc.y += vA * bf16hi_f32(gA.x);
            acc.z += vA * bf16lo_f32(gA.y);
            acc.w += vA * bf16hi_f32(gA.y);
            acc.x += vB * bf16lo_f32(gB.x);
            acc.y += vB * bf16hi_f32(gB.x);
            acc.z += vB * bf16lo_f32(gB.y);
            acc.w += vB * bf16hi_f32(gB.y);
        }
        for (; j < e; j += 4) {
            bool on = (j + q) < e;
            int2 kv = rec[on ? j + q : j];     // j < e, so rec[j] is safe
            const uint2 g = *reinterpret_cast<const uint2*>(
                h + (size_t)(kv.x & 0x1FFFF) * D_OUT + li * 4);
            float vv = on ? __int_as_float(kv.y) : 0.f;
            acc.x += vv * bf16lo_f32(g.x);
            acc.y += vv * bf16hi_f32(g.x);
            acc.z += vv * bf16lo_f32(g.y);
            acc.w += vv * bf16hi_f32(g.y);
        }
        // combine the 4 edge slots (xor 16, then 32)
        acc.x += __shfl_xor(acc.x, 16, 64);
        acc.y += __shfl_xor(acc.y, 16, 64);
        acc.z += __shfl_xor(acc.z, 16, 64);
        acc.w += __shfl_xor(acc.w, 16, 64);
        acc.x += __shfl_xor(acc.x, 32, 64);
        acc.y += __shfl_xor(acc.y, 32, 64);
        acc.z += __shfl_xor(acc.z, 32, 64);
        acc.w += __shfl_xor(acc.w, 32, 64);

        if (q == 0) {
            int gr = row0 + rl;
            if (gr < N) {
                float4 o;
                o.x = fmaxf(acc.x, 0.f);
                o.y = fmaxf(acc.y, 0.f);
                o.z = fmaxf(acc.z, 0.f);
                o.w = fmaxf(acc.w, 0.f);
                *reinterpret_cast<float4*>(out + (size_t)gr * D_OUT + li * 4) = o;
            }
        }
    }
}

// ---------------------------------------------------------------------------
extern "C" void kernel_launch(void* const* d_in, const int* in_sizes, int n_in,
                              void* d_out, int out_size, void* d_ws, size_t ws_size,
                              hipStream_t stream) {
    const float* A    = (const float*)d_in[0];
    const float* W    = (const float*)d_in[1];
    const float* vals = (const float*)d_in[2];
    const int*   rows = (const int*)d_in[3];
    const int*   cols = (const int*)d_in[4];
    float* out = (float*)d_out;

    const int N = out_size / D_OUT;                 // 100000
    const int E = in_sizes[2];                      // 1600000
    const int nbuck = (N + RPB - 1) >> RPB_SHIFT;   // 782
    const int nb = (E + EPB - 1) / EPB;             // 196

    // workspace layout (keys 8-aligned; h is bf16)
    char* ws = (char*)d_ws;
    unsigned short* h      = (unsigned short*)ws;                          // N*64 bf16
    int2*           keys   = (int2*)(ws + (size_t)N * D_OUT * 2);          // nbuck*GCAP int2
    unsigned short* wt     = (unsigned short*)((char*)keys + (size_t)nbuck * GCAP * 8);
    int*            cursor = (int*)((char*)wt + (size_t)D_OUT * K_DIM * 2); // nbuck*CPAD

    wt_kernel<<<(D_OUT * K_DIM + 255) / 256, 256, 0, stream>>>(W, wt, cursor, nbuck);
    gemm_kernel<<<(N + 63) / 64, 256, 0, stream>>>(A, wt, h, N);
    part_kernel<<<nb, 256, 0, stream>>>(rows, cols, vals, cursor, keys, E, nbuck);
    sort_agg_kernel<<<nbuck, 512, 0, stream>>>(h, keys, cursor, out, N);
}

// Round 10
// 384.261 us; speedup vs baseline: 1.9025x; 1.0560x over previous
//
#include <hip/hip_runtime.h>
#include <hip/hip_bf16.h>

#define D_OUT 64
#define K_DIM 512
#define RPB 128            // rows per bucket (pow2)
#define RPB_SHIFT 7
#define EPB 8192           // edges per partition chunk
#define GCAP 3072          // keys capacity per bucket (mean 2046, +22 sigma)
#define RCAP 3072          // LDS record capacity per bucket
#define CPAD 16            // cursor padding: 16 ints = 64 B per counter
#define NBK 1024           // padded bucket-array capacity (782 actual)

using short8  = __attribute__((ext_vector_type(8))) short;
using floatx4 = __attribute__((ext_vector_type(4))) float;

__device__ inline unsigned short f32_to_bf16(float f) {
    __hip_bfloat16 b = __float2bfloat16(f);          // HW RNE cvt
    return *reinterpret_cast<unsigned short*>(&b);
}

__device__ inline unsigned int pk_bf16(float lo, float hi) {
    __hip_bfloat162 p = __float22bfloat162_rn(make_float2(lo, hi));
    return *reinterpret_cast<unsigned int*>(&p);     // low16 = lo, high16 = hi
}

__device__ inline float bf16lo_f32(unsigned int g) {   // low ushort -> f32
    return __uint_as_float(g << 16);
}
__device__ inline float bf16hi_f32(unsigned int g) {   // high ushort -> f32
    return __uint_as_float(g & 0xFFFF0000u);
}

// ---------------------------------------------------------------------------
// Wt[n][k] = bf16(W[k][n]) : 64 x 512 bf16 (64 KB, L2-resident)
// + fused cursor init (bucket segment bases, 64 B-padded)
__global__ void wt_kernel(const float* __restrict__ W, unsigned short* __restrict__ wt,
                          int* __restrict__ cursor, int nbuck) {
    int i = blockIdx.x * blockDim.x + threadIdx.x;
    if (i < D_OUT * K_DIM) {
        int n = i >> 9;
        int k = i & 511;
        wt[i] = f32_to_bf16(W[k * D_OUT + n]);
    }
    if (i < nbuck) cursor[i * CPAD] = i * GCAP;
}

// ---------------------------------------------------------------------------
// FUSED gemm + part. The two are data-independent (gemm: A,wt -> H; part:
// rows/cols/vals -> keys); serially they cost ~gemm + ~58 us. Fused, part's
// atomic/L2-bound blocks (dispatched FIRST, ~1/CU) co-run under the
// HBM/MFMA-bound gemm wave -> part time hides.
//   blocks [0, npart)        : part path (r8 proven, low-LDS: 8 KB static)
//   blocks [npart, npart+gb) : gemm path (r4/r8 proven, byte-identical math)
__global__ __launch_bounds__(256) void gemm_part_kernel(
    const float* __restrict__ A, const unsigned short* __restrict__ wt,
    unsigned short* __restrict__ H, int n,
    const int* __restrict__ rows, const int* __restrict__ cols,
    const float* __restrict__ vals, int* __restrict__ cursor,
    int2* __restrict__ keys, int E, int nbuck, int npart) {
    __shared__ int sm[2 * NBK];          // part path: cnt+offs (8 KB); gemm: unused

    const int tid = threadIdx.x;

    if (blockIdx.x < npart) {
        // ------------------------- part path -------------------------------
        int* cnt  = sm;
        int* offs = sm + NBK;
        const int blk = blockIdx.x;

        for (int b = tid; b < nbuck; b += 256) cnt[b] = 0;
        __syncthreads();

        const int base = blk * EPB;
#pragma unroll
        for (int i = 0; i < EPB / 256; i++) {
            int e = base + tid + i * 256;
            if (e < E) atomicAdd(&cnt[rows[e] >> RPB_SHIFT], 1);
        }
        __syncthreads();

        // ONE padded global atomic per non-empty (chunk,bucket)
        for (int b = tid; b < nbuck; b += 256) {
            int c = cnt[b];
            offs[b] = c ? atomicAdd(&cursor[b * CPAD], c) : 0;
        }
        __syncthreads();

        // scatter (bucket-grouped ~84 B contiguous runs)
#pragma unroll
        for (int i = 0; i < EPB / 256; i++) {
            int e = base + tid + i * 256;
            if (e < E) {
                int r = rows[e];
                int c = cols[e];
                float v = vals[e];
                int b = r >> RPB_SHIFT;
                int p = atomicAdd(&offs[b], 1);
                if (p < (b + 1) * GCAP)      // (practically impossible) overflow guard
                    keys[p] = make_int2(c | ((r & (RPB - 1)) << 17), __float_as_int(v));
            }
        }
        return;
    }

    // --------------------------- gemm path ---------------------------------
    const int gb   = blockIdx.x - npart;
    const int wv   = tid >> 6;
    const int lane = tid & 63;
    const int ln   = lane & 15;
    const int quad = lane >> 4;
    const int row0 = gb * 64 + wv * 16;

    int arow = row0 + ln;
    if (arow >= n) arow = n - 1;          // clamp (stores guarded)
    const float* Arow = A + (size_t)arow * K_DIM;
    const unsigned short* wb = wt + (size_t)ln * K_DIM;

    floatx4 acc0 = {0.f, 0.f, 0.f, 0.f};
    floatx4 acc1 = {0.f, 0.f, 0.f, 0.f};
    floatx4 acc2 = {0.f, 0.f, 0.f, 0.f};
    floatx4 acc3 = {0.f, 0.f, 0.f, 0.f};

    for (int h0 = 0; h0 < K_DIM; h0 += 128) {
        float4 t[8];
#pragma unroll
        for (int s = 0; s < 4; s++) {
            t[2 * s]     = *reinterpret_cast<const float4*>(Arow + h0 + s * 32 + quad * 8);
            t[2 * s + 1] = *reinterpret_cast<const float4*>(Arow + h0 + s * 32 + quad * 8 + 4);
        }
        short8 ab[4];
#pragma unroll
        for (int s = 0; s < 4; s++) {
            float4 a0 = t[2 * s], a1 = t[2 * s + 1];
            int4 pk;
            pk.x = (int)pk_bf16(a0.x, a0.y);
            pk.y = (int)pk_bf16(a0.z, a0.w);
            pk.z = (int)pk_bf16(a1.x, a1.y);
            pk.w = (int)pk_bf16(a1.z, a1.w);
            ab[s] = *reinterpret_cast<short8*>(&pk);
        }
#pragma unroll
        for (int s = 0; s < 4; s++) {
            const int ko = h0 + s * 32 + quad * 8;
            short8 b0 = *reinterpret_cast<const short8*>(wb + ko);
            short8 b1 = *reinterpret_cast<const short8*>(wb + 16 * K_DIM + ko);
            short8 b2 = *reinterpret_cast<const short8*>(wb + 32 * K_DIM + ko);
            short8 b3 = *reinterpret_cast<const short8*>(wb + 48 * K_DIM + ko);
            acc0 = __builtin_amdgcn_mfma_f32_16x16x32_bf16(ab[s], b0, acc0, 0, 0, 0);
            acc1 = __builtin_amdgcn_mfma_f32_16x16x32_bf16(ab[s], b1, acc1, 0, 0, 0);
            acc2 = __builtin_amdgcn_mfma_f32_16x16x32_bf16(ab[s], b2, acc2, 0, 0, 0);
            acc3 = __builtin_amdgcn_mfma_f32_16x16x32_bf16(ab[s], b3, acc3, 0, 0, 0);
        }
    }

    // C/D layout: col = lane&15, row = quad*4 + reg  [m89]
#pragma unroll
    for (int r = 0; r < 4; r++) {
        int gr = row0 + quad * 4 + r;
        if (gr < n) {
            unsigned short* Hr = H + (size_t)gr * D_OUT;
            Hr[ln]      = f32_to_bf16(acc0[r]);
            Hr[16 + ln] = f32_to_bf16(acc1[r]);
            Hr[32 + ln] = f32_to_bf16(acc2[r]);
            Hr[48 + ln] = f32_to_bf16(acc3[r]);
        }
    }
}

// ---------------------------------------------------------------------------
// P4 (r8 proven, FROZEN): one block per bucket. LDS counting sort by
// row-local, then wave-per-row register accumulation, fused ReLU store.
__global__ __launch_bounds__(512) void sort_agg_kernel(
    const unsigned short* __restrict__ h, const int2* __restrict__ keys,
    const int* __restrict__ cursor, float* __restrict__ out, int N) {
    __shared__ int2 rec[RCAP];
    __shared__ int cnt[RPB];
    __shared__ int excl[RPB];
    __shared__ int cur[RPB];
    __shared__ int wtot[2];

    const int tid  = threadIdx.x;
    const int lane = tid & 63;
    const int wv   = tid >> 6;           // 0..7
    const int q    = lane >> 4;          // 0..3  : edge slot within wave
    const int li   = lane & 15;          // 0..15 : 4 cols per lane
    const int b    = blockIdx.x;

    const int start = b * GCAP;
    int m = cursor[b * CPAD] - start;    // final cursor = start + count
    if (m > GCAP) m = GCAP;

    if (tid < RPB) cnt[tid] = 0;
    __syncthreads();

    // count rows
    for (int i = tid; i < m; i += 512) {
        int rl = keys[start + i].x >> 17;
        atomicAdd(&cnt[rl], 1);
    }
    __syncthreads();

    // exclusive scan of 128 counters (2 waves)
    int v = 0, x = 0;
    if (tid < RPB) {
        v = cnt[tid];
        x = v;
#pragma unroll
        for (int d = 1; d < 64; d <<= 1) {
            int y = __shfl_up(x, d, 64);
            if (lane >= d) x += y;
        }
        if (lane == 63) wtot[tid >> 6] = x;
    }
    __syncthreads();
    if (tid < RPB) {
        int base = (tid >= 64) ? wtot[0] : 0;
        int ex = base + x - v;
        excl[tid] = ex;
        cur[tid]  = ex;
    }
    __syncthreads();

    // scatter into row-sorted LDS positions
    for (int i = tid; i < m; i += 512) {
        int2 kv = keys[start + i];
        int rl = kv.x >> 17;
        int p = atomicAdd(&cur[rl], 1);
        if (p < RCAP) rec[p] = kv;
    }
    __syncthreads();

    // aggregate: wave per row; 4 edges per load instruction, 8 in flight.
    const int row0 = b * RPB;
    for (int rl = wv; rl < RPB; rl += 8) {
        int s = excl[rl];
        int e = cur[rl];                 // = excl + count
        float4 acc = {0.f, 0.f, 0.f, 0.f};
        int j = s;
        for (; j + 8 <= e; j += 8) {
            int2 kA = rec[j + q];
            int2 kB = rec[j + 4 + q];
            const uint2 gA = *reinterpret_cast<const uint2*>(
                h + (size_t)(kA.x & 0x1FFFF) * D_OUT + li * 4);
            const uint2 gB = *reinterpret_cast<const uint2*>(
                h + (size_t)(kB.x & 0x1FFFF) * D_OUT + li * 4);
            float vA = __int_as_float(kA.y);
            float vB = __int_as_float(kB.y);
            acc.x += vA * bf16lo_f32(gA.x);
            acc.y += vA * bf16hi_f32(gA.x);
            acc.z += vA * bf16lo_f32(gA.y);
            acc.w += vA * bf16hi_f32(gA.y);
            acc.x += vB * bf16lo_f32(gB.x);
            acc.y += vB * bf16hi_f32(gB.x);
            acc.z += vB * bf16lo_f32(gB.y);
            acc.w += vB * bf16hi_f32(gB.y);
        }
        for (; j < e; j += 4) {
            bool on = (j + q) < e;
            int2 kv = rec[on ? j + q : j];     // j < e, so rec[j] is safe
            const uint2 g = *reinterpret_cast<const uint2*>(
                h + (size_t)(kv.x & 0x1FFFF) * D_OUT + li * 4);
            float vv = on ? __int_as_float(kv.y) : 0.f;
            acc.x += vv * bf16lo_f32(g.x);
            acc.y += vv * bf16hi_f32(g.x);
            acc.z += vv * bf16lo_f32(g.y);
            acc.w += vv * bf16hi_f32(g.y);
        }
        // combine the 4 edge slots (xor 16, then 32)
        acc.x += __shfl_xor(acc.x, 16, 64);
        acc.y += __shfl_xor(acc.y, 16, 64);
        acc.z += __shfl_xor(acc.z, 16, 64);
        acc.w += __shfl_xor(acc.w, 16, 64);
        acc.x += __shfl_xor(acc.x, 32, 64);
        acc.y += __shfl_xor(acc.y, 32, 64);
        acc.z += __shfl_xor(acc.z, 32, 64);
        acc.w += __shfl_xor(acc.w, 32, 64);

        if (q == 0) {
            int gr = row0 + rl;
            if (gr < N) {
                float4 o;
                o.x = fmaxf(acc.x, 0.f);
                o.y = fmaxf(acc.y, 0.f);
                o.z = fmaxf(acc.z, 0.f);
                o.w = fmaxf(acc.w, 0.f);
                *reinterpret_cast<float4*>(out + (size_t)gr * D_OUT + li * 4) = o;
            }
        }
    }
}

// ---------------------------------------------------------------------------
extern "C" void kernel_launch(void* const* d_in, const int* in_sizes, int n_in,
                              void* d_out, int out_size, void* d_ws, size_t ws_size,
                              hipStream_t stream) {
    const float* A    = (const float*)d_in[0];
    const float* W    = (const float*)d_in[1];
    const float* vals = (const float*)d_in[2];
    const int*   rows = (const int*)d_in[3];
    const int*   cols = (const int*)d_in[4];
    float* out = (float*)d_out;

    const int N = out_size / D_OUT;                 // 100000
    const int E = in_sizes[2];                      // 1600000
    const int nbuck = (N + RPB - 1) >> RPB_SHIFT;   // 782
    const int nb = (E + EPB - 1) / EPB;             // 196 (part blocks)
    const int gb = (N + 63) / 64;                   // 1563 (gemm blocks)

    // workspace layout (keys 8-aligned; h is bf16)
    char* ws = (char*)d_ws;
    unsigned short* h      = (unsigned short*)ws;                          // N*64 bf16
    int2*           keys   = (int2*)(ws + (size_t)N * D_OUT * 2);          // nbuck*GCAP int2
    unsigned short* wt     = (unsigned short*)((char*)keys + (size_t)nbuck * GCAP * 8);
    int*            cursor = (int*)((char*)wt + (size_t)D_OUT * K_DIM * 2); // nbuck*CPAD

    wt_kernel<<<(D_OUT * K_DIM + 255) / 256, 256, 0, stream>>>(W, wt, cursor, nbuck);
    gemm_part_kernel<<<nb + gb, 256, 0, stream>>>(A, wt, h, N,
                                                  rows, cols, vals, cursor, keys,
                                                  E, nbuck, nb);
    sort_agg_kernel<<<nbuck, 512, 0, stream>>>(h, keys, cursor, out, N);
}

// Round 11
// 384.239 us; speedup vs baseline: 1.9026x; 1.0001x over previous
//
#include <hip/hip_runtime.h>
#include <hip/hip_bf16.h>

#define D_OUT 64
#define K_DIM 512
#define RPB 128            // rows per bucket (pow2)
#define RPB_SHIFT 7
#define EPB 8192           // edges per partition chunk
#define GCAP 3072          // keys capacity per bucket (mean 2046, +22 sigma)
#define RCAP 3072          // LDS record capacity per bucket
#define CPAD 16            // cursor padding: 16 ints = 64 B per counter
#define NBK 1024           // padded bucket-array capacity (782 actual)

using short8  = __attribute__((ext_vector_type(8))) short;
using floatx4 = __attribute__((ext_vector_type(4))) float;

__device__ inline unsigned short f32_to_bf16(float f) {
    __hip_bfloat16 b = __float2bfloat16(f);          // HW RNE cvt
    return *reinterpret_cast<unsigned short*>(&b);
}

__device__ inline unsigned int pk_bf16(float lo, float hi) {
    __hip_bfloat162 p = __float22bfloat162_rn(make_float2(lo, hi));
    return *reinterpret_cast<unsigned int*>(&p);     // low16 = lo, high16 = hi
}

__device__ inline float bf16lo_f32(unsigned int g) {   // low ushort -> f32
    return __uint_as_float(g << 16);
}
__device__ inline float bf16hi_f32(unsigned int g) {   // high ushort -> f32
    return __uint_as_float(g & 0xFFFF0000u);
}

// ---------------------------------------------------------------------------
// wf = W in MFMA B-FRAGMENT ORDER (64 KB, L2-resident):
//   wf[((nb*16 + s)*64 + lane)*8 + j] = bf16(W[k][n])
//   where k = s*32 + (lane>>4)*8 + j,  n = nb*16 + (lane&15)
// -> a wave's B load for step s is wf + s*512 + lane*8 : contiguous 1 KB
//    (8 cache lines/instr instead of 16). Same values, same operands.
// + fused cursor init (bucket segment bases, 64 B-padded)
__global__ void wt_kernel(const float* __restrict__ W, unsigned short* __restrict__ wf,
                          int* __restrict__ cursor, int nbuck) {
    int i = blockIdx.x * blockDim.x + threadIdx.x;
    if (i < D_OUT * K_DIM) {
        int j    = i & 7;
        int lane = (i >> 3) & 63;
        int s    = (i >> 9) & 15;
        int nb   = i >> 13;
        int k  = s * 32 + (lane >> 4) * 8 + j;
        int nn = nb * 16 + (lane & 15);
        wf[i] = f32_to_bf16(W[k * D_OUT + nn]);
    }
    if (i < nbuck) cursor[i * CPAD] = i * GCAP;
}

// ---------------------------------------------------------------------------
// FUSED gemm + part (r10 proven, -22 us). gemm path upgraded:
//  * fragment-ordered B (coalesced 1 KB loads, 8 trans/instr vs 16)
//  * double-row waves: each wave computes 2x16 rows, reusing each B fragment
//    for two MFMA sets -> B-load instruction count halved again.
//   blocks [0, npart)        : part path (r8 proven, 8 KB LDS)
//   blocks [npart, npart+gb) : gemm path (128 rows/block)
__global__ __launch_bounds__(256) void gemm_part_kernel(
    const float* __restrict__ A, const unsigned short* __restrict__ wf,
    unsigned short* __restrict__ H, int n,
    const int* __restrict__ rows, const int* __restrict__ cols,
    const float* __restrict__ vals, int* __restrict__ cursor,
    int2* __restrict__ keys, int E, int nbuck, int npart) {
    __shared__ int sm[2 * NBK];          // part path: cnt+offs (8 KB); gemm: unused

    const int tid = threadIdx.x;

    if (blockIdx.x < npart) {
        // ------------------------- part path (FROZEN) ----------------------
        int* cnt  = sm;
        int* offs = sm + NBK;
        const int blk = blockIdx.x;

        for (int b = tid; b < nbuck; b += 256) cnt[b] = 0;
        __syncthreads();

        const int base = blk * EPB;
#pragma unroll
        for (int i = 0; i < EPB / 256; i++) {
            int e = base + tid + i * 256;
            if (e < E) atomicAdd(&cnt[rows[e] >> RPB_SHIFT], 1);
        }
        __syncthreads();

        // ONE padded global atomic per non-empty (chunk,bucket)
        for (int b = tid; b < nbuck; b += 256) {
            int c = cnt[b];
            offs[b] = c ? atomicAdd(&cursor[b * CPAD], c) : 0;
        }
        __syncthreads();

        // scatter (bucket-grouped ~84 B contiguous runs)
#pragma unroll
        for (int i = 0; i < EPB / 256; i++) {
            int e = base + tid + i * 256;
            if (e < E) {
                int r = rows[e];
                int c = cols[e];
                float v = vals[e];
                int b = r >> RPB_SHIFT;
                int p = atomicAdd(&offs[b], 1);
                if (p < (b + 1) * GCAP)      // (practically impossible) overflow guard
                    keys[p] = make_int2(c | ((r & (RPB - 1)) << 17), __float_as_int(v));
            }
        }
        return;
    }

    // --------------------------- gemm path ---------------------------------
    const int gbk  = blockIdx.x - npart;
    const int wv   = tid >> 6;
    const int lane = tid & 63;
    const int ln   = lane & 15;
    const int quad = lane >> 4;
    const int row0 = gbk * 128 + wv * 16;    // row set 0
    const int row1 = row0 + 64;              // row set 1

    int a0 = row0 + ln; if (a0 >= n) a0 = n - 1;     // clamp (stores guarded)
    int a1 = row1 + ln; if (a1 >= n) a1 = n - 1;
    const float* Arow0 = A + (size_t)a0 * K_DIM;
    const float* Arow1 = A + (size_t)a1 * K_DIM;
    const unsigned short* wfl = wf + lane * 8;       // + sg*512 per k-step

    floatx4 accA0 = {0.f,0.f,0.f,0.f}, accA1 = {0.f,0.f,0.f,0.f};
    floatx4 accA2 = {0.f,0.f,0.f,0.f}, accA3 = {0.f,0.f,0.f,0.f};
    floatx4 accB0 = {0.f,0.f,0.f,0.f}, accB1 = {0.f,0.f,0.f,0.f};
    floatx4 accB2 = {0.f,0.f,0.f,0.f}, accB3 = {0.f,0.f,0.f,0.f};

    for (int h0 = 0; h0 < K_DIM; h0 += 128) {
        // issue all 16 A-loads for this 128-k chunk (both row sets, batched)
        float4 t0[8], t1[8];
#pragma unroll
        for (int s = 0; s < 4; s++) {
            t0[2 * s]     = *reinterpret_cast<const float4*>(Arow0 + h0 + s * 32 + quad * 8);
            t0[2 * s + 1] = *reinterpret_cast<const float4*>(Arow0 + h0 + s * 32 + quad * 8 + 4);
            t1[2 * s]     = *reinterpret_cast<const float4*>(Arow1 + h0 + s * 32 + quad * 8);
            t1[2 * s + 1] = *reinterpret_cast<const float4*>(Arow1 + h0 + s * 32 + quad * 8 + 4);
        }
        // convert to bf16 fragments (packed v_cvt_pk_bf16_f32)
        short8 ab0[4], ab1[4];
#pragma unroll
        for (int s = 0; s < 4; s++) {
            float4 x0 = t0[2 * s], x1 = t0[2 * s + 1];
            int4 pk;
            pk.x = (int)pk_bf16(x0.x, x0.y);
            pk.y = (int)pk_bf16(x0.z, x0.w);
            pk.z = (int)pk_bf16(x1.x, x1.y);
            pk.w = (int)pk_bf16(x1.z, x1.w);
            ab0[s] = *reinterpret_cast<short8*>(&pk);
            float4 y0 = t1[2 * s], y1 = t1[2 * s + 1];
            int4 qk;
            qk.x = (int)pk_bf16(y0.x, y0.y);
            qk.y = (int)pk_bf16(y0.z, y0.w);
            qk.z = (int)pk_bf16(y1.x, y1.y);
            qk.w = (int)pk_bf16(y1.z, y1.w);
            ab1[s] = *reinterpret_cast<short8*>(&qk);
        }
        // MFMA: B fragment loaded once, used by BOTH row sets
#pragma unroll
        for (int s = 0; s < 4; s++) {
            const unsigned short* base = wfl + h0 * 16 + s * 512;  // sg=(h0/32+s)
            short8 b0 = *reinterpret_cast<const short8*>(base);
            short8 b1 = *reinterpret_cast<const short8*>(base + 8192);
            short8 b2 = *reinterpret_cast<const short8*>(base + 16384);
            short8 b3 = *reinterpret_cast<const short8*>(base + 24576);
            accA0 = __builtin_amdgcn_mfma_f32_16x16x32_bf16(ab0[s], b0, accA0, 0, 0, 0);
            accA1 = __builtin_amdgcn_mfma_f32_16x16x32_bf16(ab0[s], b1, accA1, 0, 0, 0);
            accA2 = __builtin_amdgcn_mfma_f32_16x16x32_bf16(ab0[s], b2, accA2, 0, 0, 0);
            accA3 = __builtin_amdgcn_mfma_f32_16x16x32_bf16(ab0[s], b3, accA3, 0, 0, 0);
            accB0 = __builtin_amdgcn_mfma_f32_16x16x32_bf16(ab1[s], b0, accB0, 0, 0, 0);
            accB1 = __builtin_amdgcn_mfma_f32_16x16x32_bf16(ab1[s], b1, accB1, 0, 0, 0);
            accB2 = __builtin_amdgcn_mfma_f32_16x16x32_bf16(ab1[s], b2, accB2, 0, 0, 0);
            accB3 = __builtin_amdgcn_mfma_f32_16x16x32_bf16(ab1[s], b3, accB3, 0, 0, 0);
        }
    }

    // C/D layout: col = lane&15, row = quad*4 + reg  [m89]
#pragma unroll
    for (int r = 0; r < 4; r++) {
        int gr = row0 + quad * 4 + r;
        if (gr < n) {
            unsigned short* Hr = H + (size_t)gr * D_OUT;
            Hr[ln]      = f32_to_bf16(accA0[r]);
            Hr[16 + ln] = f32_to_bf16(accA1[r]);
            Hr[32 + ln] = f32_to_bf16(accA2[r]);
            Hr[48 + ln] = f32_to_bf16(accA3[r]);
        }
    }
#pragma unroll
    for (int r = 0; r < 4; r++) {
        int gr = row1 + quad * 4 + r;
        if (gr < n) {
            unsigned short* Hr = H + (size_t)gr * D_OUT;
            Hr[ln]      = f32_to_bf16(accB0[r]);
            Hr[16 + ln] = f32_to_bf16(accB1[r]);
            Hr[32 + ln] = f32_to_bf16(accB2[r]);
            Hr[48 + ln] = f32_to_bf16(accB3[r]);
        }
    }
}

// ---------------------------------------------------------------------------
// P4 (r8 proven, FROZEN): one block per bucket. LDS counting sort by
// row-local, then wave-per-row register accumulation, fused ReLU store.
__global__ __launch_bounds__(512) void sort_agg_kernel(
    const unsigned short* __restrict__ h, const int2* __restrict__ keys,
    const int* __restrict__ cursor, float* __restrict__ out, int N) {
    __shared__ int2 rec[RCAP];
    __shared__ int cnt[RPB];
    __shared__ int excl[RPB];
    __shared__ int cur[RPB];
    __shared__ int wtot[2];

    const int tid  = threadIdx.x;
    const int lane = tid & 63;
    const int wv   = tid >> 6;           // 0..7
    const int q    = lane >> 4;          // 0..3  : edge slot within wave
    const int li   = lane & 15;          // 0..15 : 4 cols per lane
    const int b    = blockIdx.x;

    const int start = b * GCAP;
    int m = cursor[b * CPAD] - start;    // final cursor = start + count
    if (m > GCAP) m = GCAP;

    if (tid < RPB) cnt[tid] = 0;
    __syncthreads();

    // count rows
    for (int i = tid; i < m; i += 512) {
        int rl = keys[start + i].x >> 17;
        atomicAdd(&cnt[rl], 1);
    }
    __syncthreads();

    // exclusive scan of 128 counters (2 waves)
    int v = 0, x = 0;
    if (tid < RPB) {
        v = cnt[tid];
        x = v;
#pragma unroll
        for (int d = 1; d < 64; d <<= 1) {
            int y = __shfl_up(x, d, 64);
            if (lane >= d) x += y;
        }
        if (lane == 63) wtot[tid >> 6] = x;
    }
    __syncthreads();
    if (tid < RPB) {
        int base = (tid >= 64) ? wtot[0] : 0;
        int ex = base + x - v;
        excl[tid] = ex;
        cur[tid]  = ex;
    }
    __syncthreads();

    // scatter into row-sorted LDS positions
    for (int i = tid; i < m; i += 512) {
        int2 kv = keys[start + i];
        int rl = kv.x >> 17;
        int p = atomicAdd(&cur[rl], 1);
        if (p < RCAP) rec[p] = kv;
    }
    __syncthreads();

    // aggregate: wave per row; 4 edges per load instruction, 8 in flight.
    const int row0 = b * RPB;
    for (int rl = wv; rl < RPB; rl += 8) {
        int s = excl[rl];
        int e = cur[rl];                 // = excl + count
        float4 acc = {0.f, 0.f, 0.f, 0.f};
        int j = s;
        for (; j + 8 <= e; j += 8) {
            int2 kA = rec[j + q];
            int2 kB = rec[j + 4 + q];
            const uint2 gA = *reinterpret_cast<const uint2*>(
                h + (size_t)(kA.x & 0x1FFFF) * D_OUT + li * 4);
            const uint2 gB = *reinterpret_cast<const uint2*>(
                h + (size_t)(kB.x & 0x1FFFF) * D_OUT + li * 4);
            float vA = __int_as_float(kA.y);
            float vB = __int_as_float(kB.y);
            acc.x += vA * bf16lo_f32(gA.x);
            acc.y += vA * bf16hi_f32(gA.x);
            acc.z += vA * bf16lo_f32(gA.y);
            acc.w += vA * bf16hi_f32(gA.y);
            acc.x += vB * bf16lo_f32(gB.x);
            acc.y += vB * bf16hi_f32(gB.x);
            acc.z += vB * bf16lo_f32(gB.y);
            acc.w += vB * bf16hi_f32(gB.y);
        }
        for (; j < e; j += 4) {
            bool on = (j + q) < e;
            int2 kv = rec[on ? j + q : j];     // j < e, so rec[j] is safe
            const uint2 g = *reinterpret_cast<const uint2*>(
                h + (size_t)(kv.x & 0x1FFFF) * D_OUT + li * 4);
            float vv = on ? __int_as_float(kv.y) : 0.f;
            acc.x += vv * bf16lo_f32(g.x);
            acc.y += vv * bf16hi_f32(g.x);
            acc.z += vv * bf16lo_f32(g.y);
            acc.w += vv * bf16hi_f32(g.y);
        }
        // combine the 4 edge slots (xor 16, then 32)
        acc.x += __shfl_xor(acc.x, 16, 64);
        acc.y += __shfl_xor(acc.y, 16, 64);
        acc.z += __shfl_xor(acc.z, 16, 64);
        acc.w += __shfl_xor(acc.w, 16, 64);
        acc.x += __shfl_xor(acc.x, 32, 64);
        acc.y += __shfl_xor(acc.y, 32, 64);
        acc.z += __shfl_xor(acc.z, 32, 64);
        acc.w += __shfl_xor(acc.w, 32, 64);

        if (q == 0) {
            int gr = row0 + rl;
            if (gr < N) {
                float4 o;
                o.x = fmaxf(acc.x, 0.f);
                o.y = fmaxf(acc.y, 0.f);
                o.z = fmaxf(acc.z, 0.f);
                o.w = fmaxf(acc.w, 0.f);
                *reinterpret_cast<float4*>(out + (size_t)gr * D_OUT + li * 4) = o;
            }
        }
    }
}

// ---------------------------------------------------------------------------
extern "C" void kernel_launch(void* const* d_in, const int* in_sizes, int n_in,
                              void* d_out, int out_size, void* d_ws, size_t ws_size,
                              hipStream_t stream) {
    const float* A    = (const float*)d_in[0];
    const float* W    = (const float*)d_in[1];
    const float* vals = (const float*)d_in[2];
    const int*   rows = (const int*)d_in[3];
    const int*   cols = (const int*)d_in[4];
    float* out = (float*)d_out;

    const int N = out_size / D_OUT;                 // 100000
    const int E = in_sizes[2];                      // 1600000
    const int nbuck = (N + RPB - 1) >> RPB_SHIFT;   // 782
    const int nb = (E + EPB - 1) / EPB;             // 196 (part blocks)
    const int gb = (N + 127) / 128;                 // 782 (gemm blocks, 128 rows each)

    // workspace layout (keys 8-aligned; h is bf16)
    char* ws = (char*)d_ws;
    unsigned short* h      = (unsigned short*)ws;                          // N*64 bf16
    int2*           keys   = (int2*)(ws + (size_t)N * D_OUT * 2);          // nbuck*GCAP int2
    unsigned short* wf     = (unsigned short*)((char*)keys + (size_t)nbuck * GCAP * 8);
    int*            cursor = (int*)((char*)wf + (size_t)D_OUT * K_DIM * 2); // nbuck*CPAD

    wt_kernel<<<(D_OUT * K_DIM + 255) / 256, 256, 0, stream>>>(W, wf, cursor, nbuck);
    gemm_part_kernel<<<nb + gb, 256, 0, stream>>>(A, wf, h, N,
                                                  rows, cols, vals, cursor, keys,
                                                  E, nbuck, nb);
    sort_agg_kernel<<<nbuck, 512, 0, stream>>>(h, keys, cursor, out, N);
}

// Round 12
// 376.707 us; speedup vs baseline: 1.9407x; 1.0200x over previous
//
#include <hip/hip_runtime.h>
#include <hip/hip_bf16.h>

#define D_OUT 64
#define K_DIM 512
#define RPB 128            // rows per bucket (pow2)
#define RPB_SHIFT 7
#define EPB 8192           // edges per partition chunk
#define GCAP 3072          // keys capacity per bucket (mean 2046, +22 sigma)
#define RCAP 3072          // LDS record capacity per bucket
#define CPAD 16            // cursor padding: 16 ints = 64 B per counter
#define NBK 1024           // padded bucket-array capacity (782 actual)

using short8  = __attribute__((ext_vector_type(8))) short;
using floatx4 = __attribute__((ext_vector_type(4))) float;

__device__ inline unsigned short f32_to_bf16(float f) {
    __hip_bfloat16 b = __float2bfloat16(f);          // HW RNE cvt
    return *reinterpret_cast<unsigned short*>(&b);
}

__device__ inline unsigned int pk_bf16(float lo, float hi) {
    __hip_bfloat162 p = __float22bfloat162_rn(make_float2(lo, hi));
    return *reinterpret_cast<unsigned int*>(&p);     // low16 = lo, high16 = hi
}

__device__ inline float bf16lo_f32(unsigned int g) {   // low ushort -> f32
    return __uint_as_float(g << 16);
}
__device__ inline float bf16hi_f32(unsigned int g) {   // high ushort -> f32
    return __uint_as_float(g & 0xFFFF0000u);
}

// ---------------------------------------------------------------------------
// wf = W in MFMA B-FRAGMENT ORDER (64 KB, L2-resident):
//   wf[((nb*16 + s)*64 + lane)*8 + j] = bf16(W[k][n])
//   where k = s*32 + (lane>>4)*8 + j,  n = nb*16 + (lane&15)
// -> a wave's B load for step s is wf + s*512 + lane*8 : contiguous 1 KB.
// + fused cursor init (bucket segment bases, 64 B-padded)
__global__ void wt_kernel(const float* __restrict__ W, unsigned short* __restrict__ wf,
                          int* __restrict__ cursor, int nbuck) {
    int i = blockIdx.x * blockDim.x + threadIdx.x;
    if (i < D_OUT * K_DIM) {
        int j    = i & 7;
        int lane = (i >> 3) & 63;
        int s    = (i >> 9) & 15;
        int nb   = i >> 13;
        int k  = s * 32 + (lane >> 4) * 8 + j;
        int nn = nb * 16 + (lane & 15);
        wf[i] = f32_to_bf16(W[k * D_OUT + nn]);
    }
    if (i < nbuck) cursor[i * CPAD] = i * GCAP;
}

// ---------------------------------------------------------------------------
// FUSED gemm + part. Body identical to r11. ONE change: __launch_bounds__
// (256, 4) -> VGPR cap raised 68 -> 128/lane so the register allocator can
// keep the batched loads (t0[8]+t1[8]=32 VGPR) + 8 acc (32 VGPR) live and
// actually pipeline, instead of serializing to hit 8-waves/SIMD (r10/r11:
// VGPR=60/68, MfmaUtil 1.8%, three structural changes all null because
// regalloc flattened them). Occupancy floor 16 waves/CU > measured 7-10.
__global__ __launch_bounds__(256, 4) void gemm_part_kernel(
    const float* __restrict__ A, const unsigned short* __restrict__ wf,
    unsigned short* __restrict__ H, int n,
    const int* __restrict__ rows, const int* __restrict__ cols,
    const float* __restrict__ vals, int* __restrict__ cursor,
    int2* __restrict__ keys, int E, int nbuck, int npart) {
    __shared__ int sm[2 * NBK];          // part path: cnt+offs (8 KB); gemm: unused

    const int tid = threadIdx.x;

    if (blockIdx.x < npart) {
        // ------------------------- part path (FROZEN) ----------------------
        int* cnt  = sm;
        int* offs = sm + NBK;
        const int blk = blockIdx.x;

        for (int b = tid; b < nbuck; b += 256) cnt[b] = 0;
        __syncthreads();

        const int base = blk * EPB;
#pragma unroll
        for (int i = 0; i < EPB / 256; i++) {
            int e = base + tid + i * 256;
            if (e < E) atomicAdd(&cnt[rows[e] >> RPB_SHIFT], 1);
        }
        __syncthreads();

        // ONE padded global atomic per non-empty (chunk,bucket)
        for (int b = tid; b < nbuck; b += 256) {
            int c = cnt[b];
            offs[b] = c ? atomicAdd(&cursor[b * CPAD], c) : 0;
        }
        __syncthreads();

        // scatter (bucket-grouped ~84 B contiguous runs)
#pragma unroll
        for (int i = 0; i < EPB / 256; i++) {
            int e = base + tid + i * 256;
            if (e < E) {
                int r = rows[e];
                int c = cols[e];
                float v = vals[e];
                int b = r >> RPB_SHIFT;
                int p = atomicAdd(&offs[b], 1);
                if (p < (b + 1) * GCAP)      // (practically impossible) overflow guard
                    keys[p] = make_int2(c | ((r & (RPB - 1)) << 17), __float_as_int(v));
            }
        }
        return;
    }

    // --------------------------- gemm path ---------------------------------
    const int gbk  = blockIdx.x - npart;
    const int wv   = tid >> 6;
    const int lane = tid & 63;
    const int ln   = lane & 15;
    const int quad = lane >> 4;
    const int row0 = gbk * 128 + wv * 16;    // row set 0
    const int row1 = row0 + 64;              // row set 1

    int a0 = row0 + ln; if (a0 >= n) a0 = n - 1;     // clamp (stores guarded)
    int a1 = row1 + ln; if (a1 >= n) a1 = n - 1;
    const float* Arow0 = A + (size_t)a0 * K_DIM;
    const float* Arow1 = A + (size_t)a1 * K_DIM;
    const unsigned short* wfl = wf + lane * 8;       // + sg*512 per k-step

    floatx4 accA0 = {0.f,0.f,0.f,0.f}, accA1 = {0.f,0.f,0.f,0.f};
    floatx4 accA2 = {0.f,0.f,0.f,0.f}, accA3 = {0.f,0.f,0.f,0.f};
    floatx4 accB0 = {0.f,0.f,0.f,0.f}, accB1 = {0.f,0.f,0.f,0.f};
    floatx4 accB2 = {0.f,0.f,0.f,0.f}, accB3 = {0.f,0.f,0.f,0.f};

    for (int h0 = 0; h0 < K_DIM; h0 += 128) {
        // issue all 16 A-loads for this 128-k chunk (both row sets, batched)
        float4 t0[8], t1[8];
#pragma unroll
        for (int s = 0; s < 4; s++) {
            t0[2 * s]     = *reinterpret_cast<const float4*>(Arow0 + h0 + s * 32 + quad * 8);
            t0[2 * s + 1] = *reinterpret_cast<const float4*>(Arow0 + h0 + s * 32 + quad * 8 + 4);
            t1[2 * s]     = *reinterpret_cast<const float4*>(Arow1 + h0 + s * 32 + quad * 8);
            t1[2 * s + 1] = *reinterpret_cast<const float4*>(Arow1 + h0 + s * 32 + quad * 8 + 4);
        }
        // convert to bf16 fragments (packed v_cvt_pk_bf16_f32)
        short8 ab0[4], ab1[4];
#pragma unroll
        for (int s = 0; s < 4; s++) {
            float4 x0 = t0[2 * s], x1 = t0[2 * s + 1];
            int4 pk;
            pk.x = (int)pk_bf16(x0.x, x0.y);
            pk.y = (int)pk_bf16(x0.z, x0.w);
            pk.z = (int)pk_bf16(x1.x, x1.y);
            pk.w = (int)pk_bf16(x1.z, x1.w);
            ab0[s] = *reinterpret_cast<short8*>(&pk);
            float4 y0 = t1[2 * s], y1 = t1[2 * s + 1];
            int4 qk;
            qk.x = (int)pk_bf16(y0.x, y0.y);
            qk.y = (int)pk_bf16(y0.z, y0.w);
            qk.z = (int)pk_bf16(y1.x, y1.y);
            qk.w = (int)pk_bf16(y1.z, y1.w);
            ab1[s] = *reinterpret_cast<short8*>(&qk);
        }
        // MFMA: B fragment loaded once, used by BOTH row sets
#pragma unroll
        for (int s = 0; s < 4; s++) {
            const unsigned short* base = wfl + h0 * 16 + s * 512;  // sg=(h0/32+s)
            short8 b0 = *reinterpret_cast<const short8*>(base);
            short8 b1 = *reinterpret_cast<const short8*>(base + 8192);
            short8 b2 = *reinterpret_cast<const short8*>(base + 16384);
            short8 b3 = *reinterpret_cast<const short8*>(base + 24576);
            accA0 = __builtin_amdgcn_mfma_f32_16x16x32_bf16(ab0[s], b0, accA0, 0, 0, 0);
            accA1 = __builtin_amdgcn_mfma_f32_16x16x32_bf16(ab0[s], b1, accA1, 0, 0, 0);
            accA2 = __builtin_amdgcn_mfma_f32_16x16x32_bf16(ab0[s], b2, accA2, 0, 0, 0);
            accA3 = __builtin_amdgcn_mfma_f32_16x16x32_bf16(ab0[s], b3, accA3, 0, 0, 0);
            accB0 = __builtin_amdgcn_mfma_f32_16x16x32_bf16(ab1[s], b0, accB0, 0, 0, 0);
            accB1 = __builtin_amdgcn_mfma_f32_16x16x32_bf16(ab1[s], b1, accB1, 0, 0, 0);
            accB2 = __builtin_amdgcn_mfma_f32_16x16x32_bf16(ab1[s], b2, accB2, 0, 0, 0);
            accB3 = __builtin_amdgcn_mfma_f32_16x16x32_bf16(ab1[s], b3, accB3, 0, 0, 0);
        }
    }

    // C/D layout: col = lane&15, row = quad*4 + reg  [m89]
#pragma unroll
    for (int r = 0; r < 4; r++) {
        int gr = row0 + quad * 4 + r;
        if (gr < n) {
            unsigned short* Hr = H + (size_t)gr * D_OUT;
            Hr[ln]      = f32_to_bf16(accA0[r]);
            Hr[16 + ln] = f32_to_bf16(accA1[r]);
            Hr[32 + ln] = f32_to_bf16(accA2[r]);
            Hr[48 + ln] = f32_to_bf16(accA3[r]);
        }
    }
#pragma unroll
    for (int r = 0; r < 4; r++) {
        int gr = row1 + quad * 4 + r;
        if (gr < n) {
            unsigned short* Hr = H + (size_t)gr * D_OUT;
            Hr[ln]      = f32_to_bf16(accB0[r]);
            Hr[16 + ln] = f32_to_bf16(accB1[r]);
            Hr[32 + ln] = f32_to_bf16(accB2[r]);
            Hr[48 + ln] = f32_to_bf16(accB3[r]);
        }
    }
}

// ---------------------------------------------------------------------------
// P4 (r8 proven, FROZEN): one block per bucket. LDS counting sort by
// row-local, then wave-per-row register accumulation, fused ReLU store.
__global__ __launch_bounds__(512) void sort_agg_kernel(
    const unsigned short* __restrict__ h, const int2* __restrict__ keys,
    const int* __restrict__ cursor, float* __restrict__ out, int N) {
    __shared__ int2 rec[RCAP];
    __shared__ int cnt[RPB];
    __shared__ int excl[RPB];
    __shared__ int cur[RPB];
    __shared__ int wtot[2];

    const int tid  = threadIdx.x;
    const int lane = tid & 63;
    const int wv   = tid >> 6;           // 0..7
    const int q    = lane >> 4;          // 0..3  : edge slot within wave
    const int li   = lane & 15;          // 0..15 : 4 cols per lane
    const int b    = blockIdx.x;

    const int start = b * GCAP;
    int m = cursor[b * CPAD] - start;    // final cursor = start + count
    if (m > GCAP) m = GCAP;

    if (tid < RPB) cnt[tid] = 0;
    __syncthreads();

    // count rows
    for (int i = tid; i < m; i += 512) {
        int rl = keys[start + i].x >> 17;
        atomicAdd(&cnt[rl], 1);
    }
    __syncthreads();

    // exclusive scan of 128 counters (2 waves)
    int v = 0, x = 0;
    if (tid < RPB) {
        v = cnt[tid];
        x = v;
#pragma unroll
        for (int d = 1; d < 64; d <<= 1) {
            int y = __shfl_up(x, d, 64);
            if (lane >= d) x += y;
        }
        if (lane == 63) wtot[tid >> 6] = x;
    }
    __syncthreads();
    if (tid < RPB) {
        int base = (tid >= 64) ? wtot[0] : 0;
        int ex = base + x - v;
        excl[tid] = ex;
        cur[tid]  = ex;
    }
    __syncthreads();

    // scatter into row-sorted LDS positions
    for (int i = tid; i < m; i += 512) {
        int2 kv = keys[start + i];
        int rl = kv.x >> 17;
        int p = atomicAdd(&cur[rl], 1);
        if (p < RCAP) rec[p] = kv;
    }
    __syncthreads();

    // aggregate: wave per row; 4 edges per load instruction, 8 in flight.
    const int row0 = b * RPB;
    for (int rl = wv; rl < RPB; rl += 8) {
        int s = excl[rl];
        int e = cur[rl];                 // = excl + count
        float4 acc = {0.f, 0.f, 0.f, 0.f};
        int j = s;
        for (; j + 8 <= e; j += 8) {
            int2 kA = rec[j + q];
            int2 kB = rec[j + 4 + q];
            const uint2 gA = *reinterpret_cast<const uint2*>(
                h + (size_t)(kA.x & 0x1FFFF) * D_OUT + li * 4);
            const uint2 gB = *reinterpret_cast<const uint2*>(
                h + (size_t)(kB.x & 0x1FFFF) * D_OUT + li * 4);
            float vA = __int_as_float(kA.y);
            float vB = __int_as_float(kB.y);
            acc.x += vA * bf16lo_f32(gA.x);
            acc.y += vA * bf16hi_f32(gA.x);
            acc.z += vA * bf16lo_f32(gA.y);
            acc.w += vA * bf16hi_f32(gA.y);
            acc.x += vB * bf16lo_f32(gB.x);
            acc.y += vB * bf16hi_f32(gB.x);
            acc.z += vB * bf16lo_f32(gB.y);
            acc.w += vB * bf16hi_f32(gB.y);
        }
        for (; j < e; j += 4) {
            bool on = (j + q) < e;
            int2 kv = rec[on ? j + q : j];     // j < e, so rec[j] is safe
            const uint2 g = *reinterpret_cast<const uint2*>(
                h + (size_t)(kv.x & 0x1FFFF) * D_OUT + li * 4);
            float vv = on ? __int_as_float(kv.y) : 0.f;
            acc.x += vv * bf16lo_f32(g.x);
            acc.y += vv * bf16hi_f32(g.x);
            acc.z += vv * bf16lo_f32(g.y);
            acc.w += vv * bf16hi_f32(g.y);
        }
        // combine the 4 edge slots (xor 16, then 32)
        acc.x += __shfl_xor(acc.x, 16, 64);
        acc.y += __shfl_xor(acc.y, 16, 64);
        acc.z += __shfl_xor(acc.z, 16, 64);
        acc.w += __shfl_xor(acc.w, 16, 64);
        acc.x += __shfl_xor(acc.x, 32, 64);
        acc.y += __shfl_xor(acc.y, 32, 64);
        acc.z += __shfl_xor(acc.z, 32, 64);
        acc.w += __shfl_xor(acc.w, 32, 64);

        if (q == 0) {
            int gr = row0 + rl;
            if (gr < N) {
                float4 o;
                o.x = fmaxf(acc.x, 0.f);
                o.y = fmaxf(acc.y, 0.f);
                o.z = fmaxf(acc.z, 0.f);
                o.w = fmaxf(acc.w, 0.f);
                *reinterpret_cast<float4*>(out + (size_t)gr * D_OUT + li * 4) = o;
            }
        }
    }
}

// ---------------------------------------------------------------------------
extern "C" void kernel_launch(void* const* d_in, const int* in_sizes, int n_in,
                              void* d_out, int out_size, void* d_ws, size_t ws_size,
                              hipStream_t stream) {
    const float* A    = (const float*)d_in[0];
    const float* W    = (const float*)d_in[1];
    const float* vals = (const float*)d_in[2];
    const int*   rows = (const int*)d_in[3];
    const int*   cols = (const int*)d_in[4];
    float* out = (float*)d_out;

    const int N = out_size / D_OUT;                 // 100000
    const int E = in_sizes[2];                      // 1600000
    const int nbuck = (N + RPB - 1) >> RPB_SHIFT;   // 782
    const int nb = (E + EPB - 1) / EPB;             // 196 (part blocks)
    const int gb = (N + 127) / 128;                 // 782 (gemm blocks, 128 rows each)

    // workspace layout (keys 8-aligned; h is bf16)
    char* ws = (char*)d_ws;
    unsigned short* h      = (unsigned short*)ws;                          // N*64 bf16
    int2*           keys   = (int2*)(ws + (size_t)N * D_OUT * 2);          // nbuck*GCAP int2
    unsigned short* wf     = (unsigned short*)((char*)keys + (size_t)nbuck * GCAP * 8);
    int*            cursor = (int*)((char*)wf + (size_t)D_OUT * K_DIM * 2); // nbuck*CPAD

    wt_kernel<<<(D_OUT * K_DIM + 255) / 256, 256, 0, stream>>>(W, wf, cursor, nbuck);
    gemm_part_kernel<<<nb + gb, 256, 0, stream>>>(A, wf, h, N,
                                                  rows, cols, vals, cursor, keys,
                                                  E, nbuck, nb);
    sort_agg_kernel<<<nbuck, 512, 0, stream>>>(h, keys, cursor, out, N);
}

// Round 13
// 375.681 us; speedup vs baseline: 1.9460x; 1.0027x over previous
//
#include <hip/hip_runtime.h>
#include <hip/hip_bf16.h>

#define D_OUT 64
#define K_DIM 512
#define RPB 128            // rows per bucket (pow2)
#define RPB_SHIFT 7
#define EPB 8192           // edges per partition chunk
#define GCAP 3072          // keys capacity per bucket (mean 2046, +22 sigma)
#define RCAP 3072          // LDS record capacity per bucket
#define CPAD 16            // cursor padding: 16 ints = 64 B per counter
#define NBK 1024           // padded bucket-array capacity (782 actual)
#define LROW 72            // LDS A-tile row stride in bf16 (64 + 8 pad)

using short8  = __attribute__((ext_vector_type(8))) short;
using floatx4 = __attribute__((ext_vector_type(4))) float;

__device__ inline unsigned short f32_to_bf16(float f) {
    __hip_bfloat16 b = __float2bfloat16(f);          // HW RNE cvt
    return *reinterpret_cast<unsigned short*>(&b);
}

__device__ inline unsigned int pk_bf16(float lo, float hi) {
    __hip_bfloat162 p = __float22bfloat162_rn(make_float2(lo, hi));
    return *reinterpret_cast<unsigned int*>(&p);     // low16 = lo, high16 = hi
}

__device__ inline float bf16lo_f32(unsigned int g) {   // low ushort -> f32
    return __uint_as_float(g << 16);
}
__device__ inline float bf16hi_f32(unsigned int g) {   // high ushort -> f32
    return __uint_as_float(g & 0xFFFF0000u);
}

// ---------------------------------------------------------------------------
// wf = W in MFMA B-FRAGMENT ORDER (64 KB, L2-resident):
//   wf[((nb*16 + sg)*64 + lane)*8 + j] = bf16(W[k][n])
//   k = sg*32 + (lane>>4)*8 + j,  n = nb*16 + (lane&15)
// -> a wave's B load for step sg is wf + nb*8192 + sg*512 + lane*8 (1 KB contig).
// + fused cursor init (bucket segment bases, 64 B-padded)
__global__ void wt_kernel(const float* __restrict__ W, unsigned short* __restrict__ wf,
                          int* __restrict__ cursor, int nbuck) {
    int i = blockIdx.x * blockDim.x + threadIdx.x;
    if (i < D_OUT * K_DIM) {
        int j    = i & 7;
        int lane = (i >> 3) & 63;
        int s    = (i >> 9) & 15;
        int nb   = i >> 13;
        int k  = s * 32 + (lane >> 4) * 8 + j;
        int nn = nb * 16 + (lane & 15);
        wf[i] = f32_to_bf16(W[k * D_OUT + nn]);
    }
    if (i < nbuck) cursor[i * CPAD] = i * GCAP;
}

// ---------------------------------------------------------------------------
// FUSED gemm + part. gemm path v7: A staged through LDS (reg-staged, bf16).
// Why: r10-r12 showed the A fragment-load pattern (16 lines @ 2 KB stride per
// wave-instr) + compiler-serialized batches pins gemm at 1.33 TB/s with all
// pipes <5%. Staging decouples layouts: the stage loads are row-linear --
// each instr = 4 rows x 256 B contiguous (8 fully-consumed lines) -- and
// fragments then come from ds_read_b128. Loads for chunk c issue before the
// barriers (issue-early); 4 co-resident blocks/CU overlap stage vs MFMA.
//   blocks [0, npart)        : part path (r8 proven, FROZEN; reuses LDS)
//   blocks [npart, npart+gb) : gemm path (128 rows/block)
__global__ __launch_bounds__(256, 4) void gemm_part_kernel(
    const float* __restrict__ A, const unsigned short* __restrict__ wf,
    unsigned short* __restrict__ H, int n,
    const int* __restrict__ rows, const int* __restrict__ cols,
    const float* __restrict__ vals, int* __restrict__ cursor,
    int2* __restrict__ keys, int E, int nbuck, int npart) {
    __shared__ __align__(16) unsigned short ats[128 * LROW];  // 18.4 KB

    const int tid = threadIdx.x;

    if (blockIdx.x < npart) {
        // ------------------------- part path (FROZEN) ----------------------
        int* cnt  = (int*)ats;
        int* offs = cnt + NBK;
        const int blk = blockIdx.x;

        for (int b = tid; b < nbuck; b += 256) cnt[b] = 0;
        __syncthreads();

        const int base = blk * EPB;
#pragma unroll
        for (int i = 0; i < EPB / 256; i++) {
            int e = base + tid + i * 256;
            if (e < E) atomicAdd(&cnt[rows[e] >> RPB_SHIFT], 1);
        }
        __syncthreads();

        // ONE padded global atomic per non-empty (chunk,bucket)
        for (int b = tid; b < nbuck; b += 256) {
            int c = cnt[b];
            offs[b] = c ? atomicAdd(&cursor[b * CPAD], c) : 0;
        }
        __syncthreads();

        // scatter (bucket-grouped ~84 B contiguous runs)
#pragma unroll
        for (int i = 0; i < EPB / 256; i++) {
            int e = base + tid + i * 256;
            if (e < E) {
                int r = rows[e];
                int c = cols[e];
                float v = vals[e];
                int b = r >> RPB_SHIFT;
                int p = atomicAdd(&offs[b], 1);
                if (p < (b + 1) * GCAP)      // (practically impossible) overflow guard
                    keys[p] = make_int2(c | ((r & (RPB - 1)) << 17), __float_as_int(v));
            }
        }
        return;
    }

    // --------------------------- gemm path ---------------------------------
    const int gbk  = blockIdx.x - npart;
    const int wv   = tid >> 6;
    const int lane = tid & 63;
    const int ln   = lane & 15;
    const int quad = lane >> 4;
    const int blkrow0 = gbk * 128;
    const int row0 = blkrow0 + wv * 16;      // row set 0
    const int row1 = row0 + 64;              // row set 1

    const unsigned short* wfl = wf + lane * 8;

    // staging map: l = i*256+tid, r = l>>4 (row 0..127), seg = l&15 (16B col seg)
    const int srow = tid >> 4;               // rows advance by 16 per iter
    const int sseg = tid & 15;

    floatx4 accA0 = {0.f,0.f,0.f,0.f}, accA1 = {0.f,0.f,0.f,0.f};
    floatx4 accA2 = {0.f,0.f,0.f,0.f}, accA3 = {0.f,0.f,0.f,0.f};
    floatx4 accB0 = {0.f,0.f,0.f,0.f}, accB1 = {0.f,0.f,0.f,0.f};
    floatx4 accB2 = {0.f,0.f,0.f,0.f}, accB3 = {0.f,0.f,0.f,0.f};

    for (int c = 0; c < 8; c++) {
        // issue all 8 stage loads (4 rows x 256 B contiguous per wave-instr)
        float4 t[8];
#pragma unroll
        for (int i = 0; i < 8; i++) {
            int r = i * 16 + srow;
            int gr = blkrow0 + r; if (gr >= n) gr = n - 1;   // clamp (stores guarded)
            t[i] = *reinterpret_cast<const float4*>(
                A + (size_t)gr * K_DIM + c * 64 + sseg * 4);
        }
        __syncthreads();                     // previous chunk's reads complete
        // convert + LDS write (bf16, padded rows)
#pragma unroll
        for (int i = 0; i < 8; i++) {
            int r = i * 16 + srow;
            uint2 w;
            w.x = pk_bf16(t[i].x, t[i].y);
            w.y = pk_bf16(t[i].z, t[i].w);
            *reinterpret_cast<uint2*>(&ats[r * LROW + sseg * 4]) = w;
        }
        __syncthreads();                     // tile visible to all waves

        // MFMA: fragments from ds_read_b128; B loaded once, used by both sets
#pragma unroll
        for (int s = 0; s < 2; s++) {
            short8 a0 = *reinterpret_cast<const short8*>(
                &ats[(wv * 16 + ln) * LROW + s * 32 + quad * 8]);
            short8 a1 = *reinterpret_cast<const short8*>(
                &ats[(64 + wv * 16 + ln) * LROW + s * 32 + quad * 8]);
            const unsigned short* bb = wfl + (c * 2 + s) * 512;
            short8 b0 = *reinterpret_cast<const short8*>(bb);
            short8 b1 = *reinterpret_cast<const short8*>(bb + 8192);
            short8 b2 = *reinterpret_cast<const short8*>(bb + 16384);
            short8 b3 = *reinterpret_cast<const short8*>(bb + 24576);
            accA0 = __builtin_amdgcn_mfma_f32_16x16x32_bf16(a0, b0, accA0, 0, 0, 0);
            accA1 = __builtin_amdgcn_mfma_f32_16x16x32_bf16(a0, b1, accA1, 0, 0, 0);
            accA2 = __builtin_amdgcn_mfma_f32_16x16x32_bf16(a0, b2, accA2, 0, 0, 0);
            accA3 = __builtin_amdgcn_mfma_f32_16x16x32_bf16(a0, b3, accA3, 0, 0, 0);
            accB0 = __builtin_amdgcn_mfma_f32_16x16x32_bf16(a1, b0, accB0, 0, 0, 0);
            accB1 = __builtin_amdgcn_mfma_f32_16x16x32_bf16(a1, b1, accB1, 0, 0, 0);
            accB2 = __builtin_amdgcn_mfma_f32_16x16x32_bf16(a1, b2, accB2, 0, 0, 0);
            accB3 = __builtin_amdgcn_mfma_f32_16x16x32_bf16(a1, b3, accB3, 0, 0, 0);
        }
    }

    // C/D layout: col = lane&15, row = quad*4 + reg  [m89]
#pragma unroll
    for (int r = 0; r < 4; r++) {
        int gr = row0 + quad * 4 + r;
        if (gr < n) {
            unsigned short* Hr = H + (size_t)gr * D_OUT;
            Hr[ln]      = f32_to_bf16(accA0[r]);
            Hr[16 + ln] = f32_to_bf16(accA1[r]);
            Hr[32 + ln] = f32_to_bf16(accA2[r]);
            Hr[48 + ln] = f32_to_bf16(accA3[r]);
        }
    }
#pragma unroll
    for (int r = 0; r < 4; r++) {
        int gr = row1 + quad * 4 + r;
        if (gr < n) {
            unsigned short* Hr = H + (size_t)gr * D_OUT;
            Hr[ln]      = f32_to_bf16(accB0[r]);
            Hr[16 + ln] = f32_to_bf16(accB1[r]);
            Hr[32 + ln] = f32_to_bf16(accB2[r]);
            Hr[48 + ln] = f32_to_bf16(accB3[r]);
        }
    }
}

// ---------------------------------------------------------------------------
// P4 (r8 proven, FROZEN): one block per bucket. LDS counting sort by
// row-local, then wave-per-row register accumulation, fused ReLU store.
__global__ __launch_bounds__(512) void sort_agg_kernel(
    const unsigned short* __restrict__ h, const int2* __restrict__ keys,
    const int* __restrict__ cursor, float* __restrict__ out, int N) {
    __shared__ int2 rec[RCAP];
    __shared__ int cnt[RPB];
    __shared__ int excl[RPB];
    __shared__ int cur[RPB];
    __shared__ int wtot[2];

    const int tid  = threadIdx.x;
    const int lane = tid & 63;
    const int wv   = tid >> 6;           // 0..7
    const int q    = lane >> 4;          // 0..3  : edge slot within wave
    const int li   = lane & 15;          // 0..15 : 4 cols per lane
    const int b    = blockIdx.x;

    const int start = b * GCAP;
    int m = cursor[b * CPAD] - start;    // final cursor = start + count
    if (m > GCAP) m = GCAP;

    if (tid < RPB) cnt[tid] = 0;
    __syncthreads();

    // count rows
    for (int i = tid; i < m; i += 512) {
        int rl = keys[start + i].x >> 17;
        atomicAdd(&cnt[rl], 1);
    }
    __syncthreads();

    // exclusive scan of 128 counters (2 waves)
    int v = 0, x = 0;
    if (tid < RPB) {
        v = cnt[tid];
        x = v;
#pragma unroll
        for (int d = 1; d < 64; d <<= 1) {
            int y = __shfl_up(x, d, 64);
            if (lane >= d) x += y;
        }
        if (lane == 63) wtot[tid >> 6] = x;
    }
    __syncthreads();
    if (tid < RPB) {
        int base = (tid >= 64) ? wtot[0] : 0;
        int ex = base + x - v;
        excl[tid] = ex;
        cur[tid]  = ex;
    }
    __syncthreads();

    // scatter into row-sorted LDS positions
    for (int i = tid; i < m; i += 512) {
        int2 kv = keys[start + i];
        int rl = kv.x >> 17;
        int p = atomicAdd(&cur[rl], 1);
        if (p < RCAP) rec[p] = kv;
    }
    __syncthreads();

    // aggregate: wave per row; 4 edges per load instruction, 8 in flight.
    const int row0 = b * RPB;
    for (int rl = wv; rl < RPB; rl += 8) {
        int s = excl[rl];
        int e = cur[rl];                 // = excl + count
        float4 acc = {0.f, 0.f, 0.f, 0.f};
        int j = s;
        for (; j + 8 <= e; j += 8) {
            int2 kA = rec[j + q];
            int2 kB = rec[j + 4 + q];
            const uint2 gA = *reinterpret_cast<const uint2*>(
                h + (size_t)(kA.x & 0x1FFFF) * D_OUT + li * 4);
            const uint2 gB = *reinterpret_cast<const uint2*>(
                h + (size_t)(kB.x & 0x1FFFF) * D_OUT + li * 4);
            float vA = __int_as_float(kA.y);
            float vB = __int_as_float(kB.y);
            acc.x += vA * bf16lo_f32(gA.x);
            acc.y += vA * bf16hi_f32(gA.x);
            acc.z += vA * bf16lo_f32(gA.y);
            acc.w += vA * bf16hi_f32(gA.y);
            acc.x += vB * bf16lo_f32(gB.x);
            acc.y += vB * bf16hi_f32(gB.x);
            acc.z += vB * bf16lo_f32(gB.y);
            acc.w += vB * bf16hi_f32(gB.y);
        }
        for (; j < e; j += 4) {
            bool on = (j + q) < e;
            int2 kv = rec[on ? j + q : j];     // j < e, so rec[j] is safe
            const uint2 g = *reinterpret_cast<const uint2*>(
                h + (size_t)(kv.x & 0x1FFFF) * D_OUT + li * 4);
            float vv = on ? __int_as_float(kv.y) : 0.f;
            acc.x += vv * bf16lo_f32(g.x);
            acc.y += vv * bf16hi_f32(g.x);
            acc.z += vv * bf16lo_f32(g.y);
            acc.w += vv * bf16hi_f32(g.y);
        }
        // combine the 4 edge slots (xor 16, then 32)
        acc.x += __shfl_xor(acc.x, 16, 64);
        acc.y += __shfl_xor(acc.y, 16, 64);
        acc.z += __shfl_xor(acc.z, 16, 64);
        acc.w += __shfl_xor(acc.w, 16, 64);
        acc.x += __shfl_xor(acc.x, 32, 64);
        acc.y += __shfl_xor(acc.y, 32, 64);
        acc.z += __shfl_xor(acc.z, 32, 64);
        acc.w += __shfl_xor(acc.w, 32, 64);

        if (q == 0) {
            int gr = row0 + rl;
            if (gr < N) {
                float4 o;
                o.x = fmaxf(acc.x, 0.f);
                o.y = fmaxf(acc.y, 0.f);
                o.z = fmaxf(acc.z, 0.f);
                o.w = fmaxf(acc.w, 0.f);
                *reinterpret_cast<float4*>(out + (size_t)gr * D_OUT + li * 4) = o;
            }
        }
    }
}

// ---------------------------------------------------------------------------
extern "C" void kernel_launch(void* const* d_in, const int* in_sizes, int n_in,
                              void* d_out, int out_size, void* d_ws, size_t ws_size,
                              hipStream_t stream) {
    const float* A    = (const float*)d_in[0];
    const float* W    = (const float*)d_in[1];
    const float* vals = (const float*)d_in[2];
    const int*   rows = (const int*)d_in[3];
    const int*   cols = (const int*)d_in[4];
    float* out = (float*)d_out;

    const int N = out_size / D_OUT;                 // 100000
    const int E = in_sizes[2];                      // 1600000
    const int nbuck = (N + RPB - 1) >> RPB_SHIFT;   // 782
    const int nb = (E + EPB - 1) / EPB;             // 196 (part blocks)
    const int gb = (N + 127) / 128;                 // 782 (gemm blocks, 128 rows each)

    // workspace layout (keys 8-aligned; h is bf16)
    char* ws = (char*)d_ws;
    unsigned short* h      = (unsigned short*)ws;                          // N*64 bf16
    int2*           keys   = (int2*)(ws + (size_t)N * D_OUT * 2);          // nbuck*GCAP int2
    unsigned short* wf     = (unsigned short*)((char*)keys + (size_t)nbuck * GCAP * 8);
    int*            cursor = (int*)((char*)wf + (size_t)D_OUT * K_DIM * 2); // nbuck*CPAD

    wt_kernel<<<(D_OUT * K_DIM + 255) / 256, 256, 0, stream>>>(W, wf, cursor, nbuck);
    gemm_part_kernel<<<nb + gb, 256, 0, stream>>>(A, wf, h, N,
                                                  rows, cols, vals, cursor, keys,
                                                  E, nbuck, nb);
    sort_agg_kernel<<<nbuck, 512, 0, stream>>>(h, keys, cursor, out, N);
}